// Round 1
// baseline (1234.675 us; speedup 1.0000x reference)
//
#include <hip/hip_runtime.h>
#include <math.h>

#define PI_F 3.14159265358979323846f

// ---------------- encoder: x[16][8192][2] -> u1[64][16][8192] ----------------
__global__ __launch_bounds__(256) void enc_kernel(
    const float* __restrict__ x, const float* __restrict__ ew,
    const float* __restrict__ eb, float* __restrict__ u1)
{
    int idx = blockIdx.x * 256 + threadIdx.x;   // 64*16*2048 threads, 4 t each
    int t4 = idx & 2047;
    int b  = (idx >> 11) & 15;
    int h  = idx >> 15;
    float w0 = ew[2*h], w1 = ew[2*h+1], bb = eb[h];
    const float* xp = x + ((size_t)b*8192 + (size_t)t4*4)*2;
    float4 a = *(const float4*)xp;
    float4 c = *(const float4*)(xp + 4);
    float4 o;
    o.x = fmaf(w0, a.x, fmaf(w1, a.y, bb));
    o.y = fmaf(w0, a.z, fmaf(w1, a.w, bb));
    o.z = fmaf(w0, c.x, fmaf(w1, c.y, bb));
    o.w = fmaf(w0, c.z, fmaf(w1, c.w, bb));
    *(float4*)(u1 + ((size_t)h*16 + b)*8192 + (size_t)t4*4) = o;
}

// ---------------- S4 pass1: per-chunk states from zero init ----------------
// u layout [H][16][L]; Bc layout [H][16][NCH][32*2]
__global__ __launch_bounds__(64) void s4_pass1(
    const float* __restrict__ u, const float* __restrict__ sc, const float* __restrict__ sh,
    const float* __restrict__ log_dt, float* __restrict__ Bc,
    int H, int L, int T, int NCH)
{
    int gid = blockIdx.x * 64 + threadIdx.x;
    int c = gid % NCH;
    int tmp = gid / NCH;
    int b = tmp & 15;
    int h = tmp >> 4;
    float dt = expf(log_dt[h]);
    float e = expf(-0.5f * dt);
    float wr[32], wi[32], sr[32], si[32];
#pragma unroll
    for (int n = 0; n < 32; n++) {
        float s_, c_; sincosf(PI_F * dt * n, &s_, &c_);
        wr[n] = e * c_; wi[n] = e * s_; sr[n] = 0.f; si[n] = 0.f;
    }
    const float* up = u + ((size_t)h*16 + b)*L + (size_t)c*T;
    float scv = sc ? sc[h] : 1.f;
    float shv = sh ? sh[h] : 0.f;
    for (int t4 = 0; t4 < T/4; ++t4) {
        float4 u4 = *(const float4*)(up + t4*4);
        float uu[4] = {u4.x, u4.y, u4.z, u4.w};
#pragma unroll
        for (int k = 0; k < 4; k++) {
            float uv = fmaf(scv, uu[k], shv);
#pragma unroll
            for (int n = 0; n < 32; n++) {
                float s0 = sr[n], s1 = si[n];
                sr[n] = fmaf(wr[n], s0, fmaf(-wi[n], s1, uv));
                si[n] = fmaf(wi[n], s0, wr[n] * s1);
            }
        }
    }
    float* bp = Bc + (((size_t)h*16 + b)*NCH + c)*64;
#pragma unroll
    for (int n = 0; n < 32; n++) {
        float2 v; v.x = sr[n]; v.y = si[n];
        *(float2*)(bp + 2*n) = v;
    }
}

// ---------------- S4 mid: chunk-level scan; T is always 128 (w^128 via 7 squarings)
__global__ __launch_bounds__(64) void s4_mid(
    const float* __restrict__ log_dt, const float* __restrict__ Bc,
    float* __restrict__ Sinit, float* __restrict__ Sfinal,
    int H, int NCH)
{
    int gid = blockIdx.x * 64 + threadIdx.x;   // H*16*32
    int n = gid & 31;
    int tmp = gid >> 5;
    int b = tmp & 15;
    int h = tmp >> 4;
    float dt = expf(log_dt[h]);
    float e = expf(-0.5f * dt);
    float s_, c_; sincosf(PI_F * dt * n, &s_, &c_);
    float wr = e * c_, wi = e * s_;
#pragma unroll
    for (int i = 0; i < 7; i++) { float r = wr*wr - wi*wi; float im = 2.f*wr*wi; wr = r; wi = im; }
    float Sr = 0.f, Si = 0.f;
    size_t base = (((size_t)h*16 + b)*NCH)*64 + 2*n;
    for (int c = 0; c < NCH; c++) {
        float2 v; v.x = Sr; v.y = Si;
        *(float2*)(Sinit + base + (size_t)c*64) = v;
        float2 bc = *(const float2*)(Bc + base + (size_t)c*64);
        float r  = fmaf(wr, Sr, fmaf(-wi, Si, bc.x));
        float im = fmaf(wi, Sr, fmaf( wr, Si, bc.y));
        Sr = r; Si = im;
    }
    if (Sfinal) {
        float2 v; v.x = Sr; v.y = Si;
        *(float2*)(Sfinal + ((size_t)h*16 + b)*64 + 2*n) = v;
    }
}

// ---------------- S4 pass2: recompute chunk with init state, emit y ----------------
__global__ __launch_bounds__(64) void s4_pass2(
    const float* __restrict__ u, const float* __restrict__ sc, const float* __restrict__ sh,
    const float* __restrict__ log_dt, const float* __restrict__ C2, const float* __restrict__ Dv,
    const float* __restrict__ Sinit, float* __restrict__ y,
    int H, int L, int T, int NCH)
{
    int gid = blockIdx.x * 64 + threadIdx.x;
    int c = gid % NCH;
    int tmp = gid / NCH;
    int b = tmp & 15;
    int h = tmp >> 4;
    float dt = expf(log_dt[h]);
    float e = expf(-0.5f * dt);
    float wr[32], wi[32], cr[32], ci[32], sr[32], si[32];
#pragma unroll
    for (int n = 0; n < 32; n++) {
        float s_, c_; sincosf(PI_F * dt * n, &s_, &c_);
        wr[n] = e * c_; wi[n] = e * s_;
        float ar = -0.5f, ai = PI_F * n;
        float den = 1.f / (ar*ar + ai*ai);
        float tr = wr[n] - 1.f, ti = wi[n];
        float qr = (tr*ar + ti*ai) * den;
        float qi = (ti*ar - tr*ai) * den;
        float c2r = C2[((size_t)h*32 + n)*2], c2i = C2[((size_t)h*32 + n)*2 + 1];
        cr[n] = 2.f * (c2r*qr - c2i*qi);   // fold the 2*Re() factor into C
        ci[n] = 2.f * (c2r*qi + c2i*qr);
    }
    float Dh = Dv[h];
    const float* sp = Sinit + (((size_t)h*16 + b)*NCH + c)*64;
#pragma unroll
    for (int n = 0; n < 32; n++) { sr[n] = sp[2*n]; si[n] = sp[2*n+1]; }
    const float* up = u + ((size_t)h*16 + b)*L + (size_t)c*T;
    float*       yp = y + ((size_t)h*16 + b)*L + (size_t)c*T;
    float scv = sc ? sc[h] : 1.f;
    float shv = sh ? sh[h] : 0.f;
    for (int t4 = 0; t4 < T/4; ++t4) {
        float4 u4 = *(const float4*)(up + t4*4);
        float uu[4] = {u4.x, u4.y, u4.z, u4.w};
        float yy[4];
#pragma unroll
        for (int k = 0; k < 4; k++) {
            float uv = fmaf(scv, uu[k], shv);
            float aR = 0.f, aI = 0.f;
#pragma unroll
            for (int n = 0; n < 32; n++) {
                float s0 = sr[n], s1 = si[n];
                sr[n] = fmaf(wr[n], s0, fmaf(-wi[n], s1, uv));
                si[n] = fmaf(wi[n], s0, wr[n] * s1);
                aR = fmaf(cr[n], sr[n], aR);
                aI = fmaf(ci[n], si[n], aI);
            }
            yy[k] = fmaf(Dh, uv, aR - aI);
        }
        *(float4*)(yp + t4*4) = make_float4(yy[0], yy[1], yy[2], yy[3]);
    }
}

// ---------------- conv: stride-4 K=3 dilated, residue-plane LDS ----------------
// u [CIN][16][Lin] -> out channels [jch .. jch+CIN) of [4*CIN][16][Lout]
template<int CIN, int DIL, bool LRELU>
__global__ __launch_bounds__(256) void conv_kernel(
    const float* __restrict__ u, const float* __restrict__ w,
    const float* __restrict__ bias, float* __restrict__ out,
    int Lin, int Lout, int jch)
{
    constexpr int CC = 32;
    constexpr int PWP = 72;                 // plane stride (entries used: 68)
    __shared__ float s_in[CC * 4 * PWP];    // 36864 B
    __shared__ float s_w[CC * 64 * 3];      // 24576 B
    int tid = threadIdx.x;
    int tg = tid & 15;          // 16 t-groups of 4
    int o4 = tid >> 4;          // 16 o-groups of 4
    int t0 = blockIdx.x * 64;
    int b  = blockIdx.y;
    int og = blockIdx.z * 64;

    float acc[4][4];
#pragma unroll
    for (int oo = 0; oo < 4; oo++) {
        float bv = bias[og + o4*4 + oo];
#pragma unroll
        for (int ti = 0; ti < 4; ti++) acc[oo][ti] = bv;
    }

    for (int cc0 = 0; cc0 < CIN; cc0 += CC) {
        __syncthreads();
        // stage input: global span [4*(t0-2), 4*(t0+66)) per channel, residue-planed
        for (int idx = tid; idx < CC*272; idx += 256) {
            int c_l = idx / 272;
            int pofs = idx - c_l*272;
            int p = t0*4 - 8 + pofs;
            float v = 0.f;
            if ((unsigned)p < (unsigned)Lin)
                v = u[((size_t)(cc0 + c_l)*16 + b)*Lin + p];
            s_in[c_l*(4*PWP) + (pofs & 3)*PWP + (pofs >> 2)] = v;
        }
        // stage weights: s_w[c_l][o][k] = w[og+o][cc0+c_l][k]
        for (int idx = tid; idx < CC*64*3; idx += 256) {
            int o = idx / 96;
            int rem = idx - o*96;          // rem = c_l*3 + k
            int c_l = rem / 3;
            int k   = rem - c_l*3;
            s_w[c_l*192 + o*3 + k] = w[((size_t)(og + o)*CIN + cc0)*3 + rem];
        }
        __syncthreads();
        for (int c_l = 0; c_l < CC; c_l++) {
            float wv[4][3];
#pragma unroll
            for (int oo = 0; oo < 4; oo++)
#pragma unroll
                for (int k = 0; k < 3; k++)
                    wv[oo][k] = s_w[c_l*192 + (o4*4 + oo)*3 + k];
#pragma unroll
            for (int k = 0; k < 3; k++) {
                const int off = (k - 1) * DIL;
                const int r = off & 3;
                const int s = off >> 2;
                const float* bp = &s_in[c_l*(4*PWP) + r*PWP + (tg*4 + 2 + s)];
                float x0 = bp[0], x1 = bp[1], x2 = bp[2], x3 = bp[3];
#pragma unroll
                for (int oo = 0; oo < 4; oo++) {
                    acc[oo][0] = fmaf(wv[oo][k], x0, acc[oo][0]);
                    acc[oo][1] = fmaf(wv[oo][k], x1, acc[oo][1]);
                    acc[oo][2] = fmaf(wv[oo][k], x2, acc[oo][2]);
                    acc[oo][3] = fmaf(wv[oo][k], x3, acc[oo][3]);
                }
            }
        }
    }
#pragma unroll
    for (int oo = 0; oo < 4; oo++) {
        float v0 = acc[oo][0], v1 = acc[oo][1], v2 = acc[oo][2], v3 = acc[oo][3];
        if (LRELU) {
            v0 = v0 >= 0.f ? v0 : 0.3f*v0;
            v1 = v1 >= 0.f ? v1 : 0.3f*v1;
            v2 = v2 >= 0.f ? v2 : 0.3f*v2;
            v3 = v3 >= 0.f ? v3 : 0.3f*v3;
        }
        int ch = jch + og + o4*4 + oo;
        *(float4*)(out + ((size_t)ch*16 + b)*Lout + t0 + tg*4) =
            make_float4(v0, v1, v2, v3);
    }
}

// ---------------- BN stats: one block per channel -> scale/shift ----------------
__global__ __launch_bounds__(256) void bn_stats(
    const float* __restrict__ x, const float* __restrict__ g, const float* __restrict__ bb,
    float* __restrict__ sc, float* __restrict__ sh, int n, int gmask)
{
    int ch = blockIdx.x;
    const float* xp = x + (size_t)ch * n;
    float s1 = 0.f, s2 = 0.f;
    for (int i = threadIdx.x*4; i < n; i += 1024) {
        float4 v = *(const float4*)(xp + i);
        s1 += v.x + v.y + v.z + v.w;
        s2 += v.x*v.x + v.y*v.y + v.z*v.z + v.w*v.w;
    }
    for (int o = 32; o > 0; o >>= 1) { s1 += __shfl_down(s1, o); s2 += __shfl_down(s2, o); }
    __shared__ float p1[4], p2[4];
    int wid = threadIdx.x >> 6;
    if ((threadIdx.x & 63) == 0) { p1[wid] = s1; p2[wid] = s2; }
    __syncthreads();
    if (threadIdx.x == 0) {
        s1 = p1[0] + p1[1] + p1[2] + p1[3];
        s2 = p2[0] + p2[1] + p2[2] + p2[3];
        float m = s1 / n;
        float var = s2 / n - m*m;
        float rstd = rsqrtf(var + 1e-5f);
        float scale = g[ch & gmask] * rstd;
        sc[ch] = scale;
        sh[ch] = fmaf(-m, scale, bb[ch & gmask]);
    }
}

// ---------------- s4c final-state -> x3[:, :, 511] ----------------
__global__ __launch_bounds__(256) void s4c_last(
    const float* __restrict__ Sfinal, const float* __restrict__ x2raw,
    const float* __restrict__ sc, const float* __restrict__ sh,
    const float* __restrict__ log_dt, const float* __restrict__ C2,
    const float* __restrict__ Dv, float* __restrict__ x3last)
{
    int gid = blockIdx.x*256 + threadIdx.x;  // 16*1024
    int h = gid & 1023;
    int b = gid >> 10;
    float dt = expf(log_dt[h]);
    float e = expf(-0.5f * dt);
    const float* sp = Sfinal + ((size_t)h*16 + b)*64;
    float aR = 0.f, aI = 0.f;
#pragma unroll
    for (int n = 0; n < 32; n++) {
        float s_, c_; sincosf(PI_F * dt * n, &s_, &c_);
        float wr = e*c_, wi = e*s_;
        float ar = -0.5f, ai = PI_F * n;
        float den = 1.f / (ar*ar + ai*ai);
        float tr = wr - 1.f, ti = wi;
        float qr = (tr*ar + ti*ai) * den;
        float qi = (ti*ar - tr*ai) * den;
        float c2r = C2[((size_t)h*32 + n)*2], c2i = C2[((size_t)h*32 + n)*2 + 1];
        float cr = c2r*qr - c2i*qi, ci = c2r*qi + c2i*qr;
        aR = fmaf(cr, sp[2*n],   aR);
        aI = fmaf(ci, sp[2*n+1], aI);
    }
    float u = fmaf(sc[h], x2raw[((size_t)h*16 + b)*512 + 511], sh[h]);
    x3last[b*1024 + h] = 2.f*(aR - aI) + Dv[h]*u;
}

// ---------------- decoder head: [b] = w2 . (W1 @ x3last[b] + b1) + b2 ----------------
__global__ __launch_bounds__(256) void dec_kernel(
    const float* __restrict__ x3last, const float* __restrict__ w1, const float* __restrict__ b1,
    const float* __restrict__ w2, const float* __restrict__ b2, float* __restrict__ out)
{
    __shared__ float xs[1024];
    int b = blockIdx.x, tid = threadIdx.x;
    for (int i = tid; i < 1024; i += 256) xs[i] = x3last[b*1024 + i];
    __syncthreads();
    float z = b1[tid];
    const float* wp = w1 + (size_t)tid*1024;
    for (int i = 0; i < 1024; i += 4) {
        float4 wv = *(const float4*)(wp + i);
        z = fmaf(wv.x, xs[i],   z);
        z = fmaf(wv.y, xs[i+1], z);
        z = fmaf(wv.z, xs[i+2], z);
        z = fmaf(wv.w, xs[i+3], z);
    }
    float v = w2[tid] * z;
    for (int o = 32; o > 0; o >>= 1) v += __shfl_down(v, o);
    __shared__ float ps[4];
    if ((tid & 63) == 0) ps[tid >> 6] = v;
    __syncthreads();
    if (tid == 0) out[b] = ps[0] + ps[1] + ps[2] + ps[3] + b2[0];
}

extern "C" void kernel_launch(void* const* d_in, const int* in_sizes, int n_in,
                              void* d_out, int out_size, void* d_ws, size_t ws_size,
                              hipStream_t stream)
{
    const float* x       = (const float*)d_in[0];
    const float* enc_w   = (const float*)d_in[1];
    const float* enc_b   = (const float*)d_in[2];
    const float* s4a_ldt = (const float*)d_in[3];
    const float* s4a_C   = (const float*)d_in[4];
    const float* s4a_D   = (const float*)d_in[5];
    const float* s4b_ldt = (const float*)d_in[6];
    const float* s4b_C   = (const float*)d_in[7];
    const float* s4b_D   = (const float*)d_in[8];
    const float* s4c_ldt = (const float*)d_in[9];
    const float* s4c_C   = (const float*)d_in[10];
    const float* s4c_D   = (const float*)d_in[11];
    const float* b1w[4] = {(const float*)d_in[12], (const float*)d_in[14], (const float*)d_in[16], (const float*)d_in[18]};
    const float* b1b[4] = {(const float*)d_in[13], (const float*)d_in[15], (const float*)d_in[17], (const float*)d_in[19]};
    const float* b2w[4] = {(const float*)d_in[20], (const float*)d_in[22], (const float*)d_in[24], (const float*)d_in[26]};
    const float* b2b[4] = {(const float*)d_in[21], (const float*)d_in[23], (const float*)d_in[25], (const float*)d_in[27]};
    const float* bn1_g  = (const float*)d_in[28];
    const float* bn1_b  = (const float*)d_in[29];
    const float* bn2_g  = (const float*)d_in[30];
    const float* bn2_b  = (const float*)d_in[31];
    const float* dec1_w = (const float*)d_in[32];
    const float* dec1_b = (const float*)d_in[33];
    const float* dec2_w = (const float*)d_in[34];
    const float* dec2_b = (const float*)d_in[35];
    float* out = (float*)d_out;

    char* ws = (char*)d_ws;
    float* buf0 = (float*)(ws);                   // 8.4M floats: u1, later x2raw
    float* buf1 = (float*)(ws + 33554432);        // y1, later y2
    float* buf2 = (float*)(ws + 67108864);        // x1raw
    float* Bc   = (float*)(ws + 100663296);       // 4.2M floats
    float* Sini = (float*)(ws + 117440512);       // 4.2M floats
    float* sc1  = (float*)(ws + 134217728);
    float* sh1  = sc1 + 256;
    float* sc2  = sh1 + 256;
    float* sh2  = sc2 + 1024;
    float* x3l  = sh2 + 1024;                     // 16384 floats
    float* Sfin = x3l + 16384;                    // 1,048,576 floats

    // encoder
    enc_kernel<<<8192, 256, 0, stream>>>(x, enc_w, enc_b, buf0);

    // s4a: H=64, L=8192, T=128, NCH=64 ; u=buf0 -> y1=buf1
    s4_pass1<<<(64*16*64)/64, 64, 0, stream>>>(buf0, nullptr, nullptr, s4a_ldt, Bc, 64, 8192, 128, 64);
    s4_mid  <<<(64*16*32)/64, 64, 0, stream>>>(s4a_ldt, Bc, Sini, nullptr, 64, 64);
    s4_pass2<<<(64*16*64)/64, 64, 0, stream>>>(buf0, nullptr, nullptr, s4a_ldt, s4a_C, s4a_D, Sini, buf1, 64, 8192, 128, 64);

    // conv block1: buf1 [64][16][8192] -> buf2 [256][16][2048]
    dim3 g1(32, 16, 1);
    conv_kernel<64, 1, false><<<g1, 256, 0, stream>>>(buf1, b1w[0], b1b[0], buf2, 8192, 2048, 0);
    conv_kernel<64, 2, true ><<<g1, 256, 0, stream>>>(buf1, b1w[1], b1b[1], buf2, 8192, 2048, 64);
    conv_kernel<64, 4, true ><<<g1, 256, 0, stream>>>(buf1, b1w[2], b1b[2], buf2, 8192, 2048, 128);
    conv_kernel<64, 8, true ><<<g1, 256, 0, stream>>>(buf1, b1w[3], b1b[3], buf2, 8192, 2048, 192);
    bn_stats<<<256, 256, 0, stream>>>(buf2, bn1_g, bn1_b, sc1, sh1, 16*2048, 63);

    // s4b: H=256, L=2048, T=128, NCH=16 ; u=BN(buf2) -> y2=buf1
    s4_pass1<<<(256*16*16)/64, 64, 0, stream>>>(buf2, sc1, sh1, s4b_ldt, Bc, 256, 2048, 128, 16);
    s4_mid  <<<(256*16*32)/64, 64, 0, stream>>>(s4b_ldt, Bc, Sini, nullptr, 256, 16);
    s4_pass2<<<(256*16*16)/64, 64, 0, stream>>>(buf2, sc1, sh1, s4b_ldt, s4b_C, s4b_D, Sini, buf1, 256, 2048, 128, 16);

    // conv block2: buf1 [256][16][2048] -> buf0 [1024][16][512]
    dim3 g2(8, 16, 4);
    conv_kernel<256, 1, false><<<g2, 256, 0, stream>>>(buf1, b2w[0], b2b[0], buf0, 2048, 512, 0);
    conv_kernel<256, 2, true ><<<g2, 256, 0, stream>>>(buf1, b2w[1], b2b[1], buf0, 2048, 512, 256);
    conv_kernel<256, 4, true ><<<g2, 256, 0, stream>>>(buf1, b2w[2], b2b[2], buf0, 2048, 512, 512);
    conv_kernel<256, 8, true ><<<g2, 256, 0, stream>>>(buf1, b2w[3], b2b[3], buf0, 2048, 512, 768);
    bn_stats<<<1024, 256, 0, stream>>>(buf0, bn2_g, bn2_b, sc2, sh2, 16*512, 255);

    // s4c: H=1024, L=512, T=128, NCH=4 ; only final state needed
    s4_pass1<<<(1024*16*4)/64, 64, 0, stream>>>(buf0, sc2, sh2, s4c_ldt, Bc, 1024, 512, 128, 4);
    s4_mid  <<<(1024*16*32)/64, 64, 0, stream>>>(s4c_ldt, Bc, Sini, Sfin, 1024, 4);
    s4c_last<<<16384/256, 256, 0, stream>>>(Sfin, buf0, sc2, sh2, s4c_ldt, s4c_C, s4c_D, x3l);

    // decoder head
    dec_kernel<<<16, 256, 0, stream>>>(x3l, dec1_w, dec1_b, dec2_w, dec2_b, out);
}

// Round 2
// 571.753 us; speedup vs baseline: 2.1595x; 2.1595x over previous
//
#include <hip/hip_runtime.h>
#include <math.h>

#define PI_F 3.14159265358979323846f

typedef __attribute__((ext_vector_type(8))) short short8;
typedef __attribute__((ext_vector_type(4))) float f32x4;

__device__ __forceinline__ unsigned short f2bf(float f) {
    unsigned int u = __float_as_uint(f);
    unsigned int r = (u + 0x7fffu + ((u >> 16) & 1u)) >> 16;
    return (unsigned short)r;
}

// ---------------- encoder: x[16][8192][2] -> u1[64][16][8192] fp32 ----------------
__global__ __launch_bounds__(256) void enc_kernel(
    const float* __restrict__ x, const float* __restrict__ ew,
    const float* __restrict__ eb, float* __restrict__ u1)
{
    int idx = blockIdx.x * 256 + threadIdx.x;   // 64*16*2048 threads, 4 t each
    int t4 = idx & 2047;
    int b  = (idx >> 11) & 15;
    int h  = idx >> 15;
    float w0 = ew[2*h], w1 = ew[2*h+1], bb = eb[h];
    const float* xp = x + ((size_t)b*8192 + (size_t)t4*4)*2;
    float4 a = *(const float4*)xp;
    float4 c = *(const float4*)(xp + 4);
    float4 o;
    o.x = fmaf(w0, a.x, fmaf(w1, a.y, bb));
    o.y = fmaf(w0, a.z, fmaf(w1, a.w, bb));
    o.z = fmaf(w0, c.x, fmaf(w1, c.y, bb));
    o.w = fmaf(w0, c.z, fmaf(w1, c.w, bb));
    *(float4*)(u1 + ((size_t)h*16 + b)*8192 + (size_t)t4*4) = o;
}

// ---------------- weight prep: fp32 [O][Cin][3] -> bf16 A-frag layout [kb][o][kk] ----
__global__ __launch_bounds__(256) void prep_w(
    const float* __restrict__ w0, const float* __restrict__ w1,
    const float* __restrict__ w2, const float* __restrict__ w3,
    const float* __restrict__ w4, const float* __restrict__ w5,
    const float* __restrict__ w6, const float* __restrict__ w7,
    unsigned short* __restrict__ wprep)
{
    int id = blockIdx.y;
    const float* src; int Cin; size_t doff;
    switch (id) {
        case 0: src = w0; Cin = 64;  doff = 0;      break;
        case 1: src = w1; Cin = 64;  doff = 12288;  break;
        case 2: src = w2; Cin = 64;  doff = 24576;  break;
        case 3: src = w3; Cin = 64;  doff = 36864;  break;
        case 4: src = w4; Cin = 256; doff = 49152;  break;
        case 5: src = w5; Cin = 256; doff = 245760; break;
        case 6: src = w6; Cin = 256; doff = 442368; break;
        default: src = w7; Cin = 256; doff = 638976; break;
    }
    int e = blockIdx.x * 256 + threadIdx.x;
    if (e >= Cin * Cin * 3) return;
    int kb  = e / (Cin * 32);
    int rem = e - kb * (Cin * 32);
    int o   = rem >> 5;
    int kk  = rem & 31;
    int cch = kb / 6, t6 = kb % 6, k = t6 >> 1, chalf = t6 & 1;
    int c = cch * 64 + chalf * 32 + kk;
    wprep[doff + e] = f2bf(src[((size_t)o * Cin + c) * 3 + k]);
}

// ---------------- S4 pass1: per-chunk states from zero init ----------------
// u layout [H][16][L] fp32; Bc layout [H][16][NCH][32*2]
__global__ __launch_bounds__(64) void s4_pass1(
    const float* __restrict__ u, const float* __restrict__ sc, const float* __restrict__ sh,
    const float* __restrict__ log_dt, float* __restrict__ Bc,
    int H, int L, int T, int NCH)
{
    int gid = blockIdx.x * 64 + threadIdx.x;
    int c = gid % NCH;
    int tmp = gid / NCH;
    int b = tmp & 15;
    int h = tmp >> 4;
    float dt = expf(log_dt[h]);
    float e = expf(-0.5f * dt);
    float wr[32], wi[32], sr[32], si[32];
#pragma unroll
    for (int n = 0; n < 32; n++) {
        float s_, c_; sincosf(PI_F * dt * n, &s_, &c_);
        wr[n] = e * c_; wi[n] = e * s_; sr[n] = 0.f; si[n] = 0.f;
    }
    const float* up = u + ((size_t)h*16 + b)*L + (size_t)c*T;
    float scv = sc ? sc[h] : 1.f;
    float shv = sh ? sh[h] : 0.f;
    for (int t4 = 0; t4 < T/4; ++t4) {
        float4 u4 = *(const float4*)(up + t4*4);
        float uu[4] = {u4.x, u4.y, u4.z, u4.w};
#pragma unroll
        for (int k = 0; k < 4; k++) {
            float uv = fmaf(scv, uu[k], shv);
#pragma unroll
            for (int n = 0; n < 32; n++) {
                float s0 = sr[n], s1 = si[n];
                sr[n] = fmaf(wr[n], s0, fmaf(-wi[n], s1, uv));
                si[n] = fmaf(wi[n], s0, wr[n] * s1);
            }
        }
    }
    float* bp = Bc + (((size_t)h*16 + b)*NCH + c)*64;
#pragma unroll
    for (int n = 0; n < 32; n++) {
        float2 v; v.x = sr[n]; v.y = si[n];
        *(float2*)(bp + 2*n) = v;
    }
}

// ---------------- S4 mid: chunk-level scan; T always 128 (w^128 via 7 squarings) ----
__global__ __launch_bounds__(64) void s4_mid(
    const float* __restrict__ log_dt, const float* __restrict__ Bc,
    float* __restrict__ Sinit, float* __restrict__ Sfinal,
    int H, int NCH)
{
    int gid = blockIdx.x * 64 + threadIdx.x;   // H*16*32
    int n = gid & 31;
    int tmp = gid >> 5;
    int b = tmp & 15;
    int h = tmp >> 4;
    float dt = expf(log_dt[h]);
    float e = expf(-0.5f * dt);
    float s_, c_; sincosf(PI_F * dt * n, &s_, &c_);
    float wr = e * c_, wi = e * s_;
#pragma unroll
    for (int i = 0; i < 7; i++) { float r = wr*wr - wi*wi; float im = 2.f*wr*wi; wr = r; wi = im; }
    float Sr = 0.f, Si = 0.f;
    size_t base = (((size_t)h*16 + b)*NCH)*64 + 2*n;
    for (int c = 0; c < NCH; c++) {
        float2 v; v.x = Sr; v.y = Si;
        *(float2*)(Sinit + base + (size_t)c*64) = v;
        float2 bc = *(const float2*)(Bc + base + (size_t)c*64);
        float r  = fmaf(wr, Sr, fmaf(-wi, Si, bc.x));
        float im = fmaf(wi, Sr, fmaf( wr, Si, bc.y));
        Sr = r; Si = im;
    }
    if (Sfinal) {
        float2 v; v.x = Sr; v.y = Si;
        *(float2*)(Sfinal + ((size_t)h*16 + b)*64 + 2*n) = v;
    }
}

// ---------------- S4 pass2: recompute chunk with init state, emit y bf16 channel-last
// y layout: [16][L][H] bf16. Lane mapping: h fastest (64 consecutive h per wave).
__global__ __launch_bounds__(64) void s4_pass2(
    const float* __restrict__ u, const float* __restrict__ sc, const float* __restrict__ sh,
    const float* __restrict__ log_dt, const float* __restrict__ C2, const float* __restrict__ Dv,
    const float* __restrict__ Sinit, unsigned short* __restrict__ y,
    int H, int L, int T, int NCH, int logH)
{
    int gid = blockIdx.x * 64 + threadIdx.x;
    int h = gid & (H - 1);
    int r0 = gid >> logH;
    int b = r0 & 15;
    int c = r0 >> 4;
    float dt = expf(log_dt[h]);
    float e = expf(-0.5f * dt);
    float wr[32], wi[32], cr[32], ci[32], sr[32], si[32];
#pragma unroll
    for (int n = 0; n < 32; n++) {
        float s_, c_; sincosf(PI_F * dt * n, &s_, &c_);
        wr[n] = e * c_; wi[n] = e * s_;
        float ar = -0.5f, ai = PI_F * n;
        float den = 1.f / (ar*ar + ai*ai);
        float tr = wr[n] - 1.f, ti = wi[n];
        float qr = (tr*ar + ti*ai) * den;
        float qi = (ti*ar - tr*ai) * den;
        float c2r = C2[((size_t)h*32 + n)*2], c2i = C2[((size_t)h*32 + n)*2 + 1];
        cr[n] = 2.f * (c2r*qr - c2i*qi);
        ci[n] = 2.f * (c2r*qi + c2i*qr);
    }
    float Dh = Dv[h];
    const float* sp = Sinit + (((size_t)h*16 + b)*NCH + c)*64;
#pragma unroll
    for (int n = 0; n < 32; n++) { sr[n] = sp[2*n]; si[n] = sp[2*n+1]; }
    const float* up = u + ((size_t)h*16 + b)*L + (size_t)c*T;
    unsigned short* yp = y + ((size_t)b*L + (size_t)c*T)*H + h;
    float scv = sc ? sc[h] : 1.f;
    float shv = sh ? sh[h] : 0.f;
    for (int t4 = 0; t4 < T/4; ++t4) {
        float4 u4 = *(const float4*)(up + t4*4);
        float uu[4] = {u4.x, u4.y, u4.z, u4.w};
#pragma unroll
        for (int k = 0; k < 4; k++) {
            float uv = fmaf(scv, uu[k], shv);
            float aR = 0.f, aI = 0.f;
#pragma unroll
            for (int n = 0; n < 32; n++) {
                float s0 = sr[n], s1 = si[n];
                sr[n] = fmaf(wr[n], s0, fmaf(-wi[n], s1, uv));
                si[n] = fmaf(wi[n], s0, wr[n] * s1);
                aR = fmaf(cr[n], sr[n], aR);
                aI = fmaf(ci[n], si[n], aI);
            }
            yp[(size_t)(t4*4 + k) * H] = f2bf(fmaf(Dh, uv, aR - aI));
        }
    }
}

// ---------------- conv via MFMA bf16 ----------------
// y: [16][Lin][CIN] bf16; wp: [3*CIN/32][CIN][32] bf16 A-frag layout;
// out: fp32 [4*CIN][16][Lout], channels [jch, jch+CIN).
template<int CIN, int DIL, bool LRELU>
__global__ __launch_bounds__(256) void conv_mfma(
    const unsigned short* __restrict__ y, const unsigned short* __restrict__ wp,
    const float* __restrict__ bias, float* __restrict__ out,
    int Lin, int Lout, int jch)
{
    __shared__ unsigned short s_in[272 * 72];   // 39168 B, row stride 72 bf16 = 144 B
    int tid = threadIdx.x;
    int lane = tid & 63, wid = tid >> 6;
    int nl = lane & 15, g = lane >> 4;
    int t0 = blockIdx.x * 64;
    int b  = blockIdx.y;
    int og = blockIdx.z * 64;
    const int P0 = t0 * 4 - 8;

    f32x4 acc[4];
#pragma unroll
    for (int f = 0; f < 4; f++) acc[f] = (f32x4){0.f, 0.f, 0.f, 0.f};

    for (int cch = 0; cch < CIN / 64; ++cch) {
        if (cch) __syncthreads();
        // stage 272 rows x 64 channels (b128 copy, no transpose needed)
        for (int i = tid; i < 2176; i += 256) {
            int row = i >> 3, cg = i & 7;
            int p = P0 + row;
            uint4 v = make_uint4(0u, 0u, 0u, 0u);
            if ((unsigned)p < (unsigned)Lin)
                v = *(const uint4*)&y[((size_t)b * Lin + p) * CIN + cch * 64 + cg * 8];
            *(uint4*)&s_in[row * 72 + cg * 8] = v;
        }
        __syncthreads();
#pragma unroll
        for (int k = 0; k < 3; ++k) {
            const int off = (k - 1) * DIL + 8;
#pragma unroll
            for (int chalf = 0; chalf < 2; ++chalf) {
                int kb = cch * 6 + k * 2 + chalf;
                short8 afrag = *(const short8*)&wp[((size_t)kb * CIN + og + wid * 16 + nl) * 32 + g * 8];
#pragma unroll
                for (int f = 0; f < 4; ++f) {
                    int row = 4 * (f * 16 + nl) + off;
                    short8 bfrag = *(const short8*)&s_in[row * 72 + chalf * 32 + g * 8];
                    acc[f] = __builtin_amdgcn_mfma_f32_16x16x32_bf16(afrag, bfrag, acc[f], 0, 0, 0);
                }
            }
        }
    }
    // epilogue: C/D layout col=lane&15 (t), row=(lane>>4)*4+reg (o)
#pragma unroll
    for (int f = 0; f < 4; ++f) {
        int t = t0 + f * 16 + nl;
#pragma unroll
        for (int r = 0; r < 4; ++r) {
            int o = og + wid * 16 + g * 4 + r;
            float v = acc[f][r] + bias[o];
            if (LRELU) v = v >= 0.f ? v : 0.3f * v;
            out[((size_t)(jch + o) * 16 + b) * Lout + t] = v;
        }
    }
}

// ---------------- BN stats: one block per channel -> scale/shift ----------------
__global__ __launch_bounds__(256) void bn_stats(
    const float* __restrict__ x, const float* __restrict__ g, const float* __restrict__ bb,
    float* __restrict__ sc, float* __restrict__ sh, int n, int gmask)
{
    int ch = blockIdx.x;
    const float* xp = x + (size_t)ch * n;
    float s1 = 0.f, s2 = 0.f;
    for (int i = threadIdx.x*4; i < n; i += 1024) {
        float4 v = *(const float4*)(xp + i);
        s1 += v.x + v.y + v.z + v.w;
        s2 += v.x*v.x + v.y*v.y + v.z*v.z + v.w*v.w;
    }
    for (int o = 32; o > 0; o >>= 1) { s1 += __shfl_down(s1, o); s2 += __shfl_down(s2, o); }
    __shared__ float p1[4], p2[4];
    int wid = threadIdx.x >> 6;
    if ((threadIdx.x & 63) == 0) { p1[wid] = s1; p2[wid] = s2; }
    __syncthreads();
    if (threadIdx.x == 0) {
        s1 = p1[0] + p1[1] + p1[2] + p1[3];
        s2 = p2[0] + p2[1] + p2[2] + p2[3];
        float m = s1 / n;
        float var = s2 / n - m*m;
        float rstd = rsqrtf(var + 1e-5f);
        float scale = g[ch & gmask] * rstd;
        sc[ch] = scale;
        sh[ch] = fmaf(-m, scale, bb[ch & gmask]);
    }
}

// ---------------- s4c final-state -> x3[:, :, 511] ----------------
__global__ __launch_bounds__(256) void s4c_last(
    const float* __restrict__ Sfinal, const float* __restrict__ x2raw,
    const float* __restrict__ sc, const float* __restrict__ sh,
    const float* __restrict__ log_dt, const float* __restrict__ C2,
    const float* __restrict__ Dv, float* __restrict__ x3last)
{
    int gid = blockIdx.x*256 + threadIdx.x;  // 16*1024
    int h = gid & 1023;
    int b = gid >> 10;
    float dt = expf(log_dt[h]);
    float e = expf(-0.5f * dt);
    const float* sp = Sfinal + ((size_t)h*16 + b)*64;
    float aR = 0.f, aI = 0.f;
#pragma unroll
    for (int n = 0; n < 32; n++) {
        float s_, c_; sincosf(PI_F * dt * n, &s_, &c_);
        float wr = e*c_, wi = e*s_;
        float ar = -0.5f, ai = PI_F * n;
        float den = 1.f / (ar*ar + ai*ai);
        float tr = wr - 1.f, ti = wi;
        float qr = (tr*ar + ti*ai) * den;
        float qi = (ti*ar - tr*ai) * den;
        float c2r = C2[((size_t)h*32 + n)*2], c2i = C2[((size_t)h*32 + n)*2 + 1];
        float crv = c2r*qr - c2i*qi, civ = c2r*qi + c2i*qr;
        aR = fmaf(crv, sp[2*n],   aR);
        aI = fmaf(civ, sp[2*n+1], aI);
    }
    float u = fmaf(sc[h], x2raw[((size_t)h*16 + b)*512 + 511], sh[h]);
    x3last[b*1024 + h] = 2.f*(aR - aI) + Dv[h]*u;
}

// ---------------- decoder head ----------------
__global__ __launch_bounds__(256) void dec_kernel(
    const float* __restrict__ x3last, const float* __restrict__ w1, const float* __restrict__ b1,
    const float* __restrict__ w2, const float* __restrict__ b2, float* __restrict__ out)
{
    __shared__ float xs[1024];
    int b = blockIdx.x, tid = threadIdx.x;
    for (int i = tid; i < 1024; i += 256) xs[i] = x3last[b*1024 + i];
    __syncthreads();
    float z = b1[tid];
    const float* wpt = w1 + (size_t)tid*1024;
    for (int i = 0; i < 1024; i += 4) {
        float4 wv = *(const float4*)(wpt + i);
        z = fmaf(wv.x, xs[i],   z);
        z = fmaf(wv.y, xs[i+1], z);
        z = fmaf(wv.z, xs[i+2], z);
        z = fmaf(wv.w, xs[i+3], z);
    }
    float v = w2[tid] * z;
    for (int o = 32; o > 0; o >>= 1) v += __shfl_down(v, o);
    __shared__ float ps[4];
    if ((tid & 63) == 0) ps[tid >> 6] = v;
    __syncthreads();
    if (tid == 0) out[b] = ps[0] + ps[1] + ps[2] + ps[3] + b2[0];
}

extern "C" void kernel_launch(void* const* d_in, const int* in_sizes, int n_in,
                              void* d_out, int out_size, void* d_ws, size_t ws_size,
                              hipStream_t stream)
{
    const float* x       = (const float*)d_in[0];
    const float* enc_w   = (const float*)d_in[1];
    const float* enc_b   = (const float*)d_in[2];
    const float* s4a_ldt = (const float*)d_in[3];
    const float* s4a_C   = (const float*)d_in[4];
    const float* s4a_D   = (const float*)d_in[5];
    const float* s4b_ldt = (const float*)d_in[6];
    const float* s4b_C   = (const float*)d_in[7];
    const float* s4b_D   = (const float*)d_in[8];
    const float* s4c_ldt = (const float*)d_in[9];
    const float* s4c_C   = (const float*)d_in[10];
    const float* s4c_D   = (const float*)d_in[11];
    const float* b1w[4] = {(const float*)d_in[12], (const float*)d_in[14], (const float*)d_in[16], (const float*)d_in[18]};
    const float* b1b[4] = {(const float*)d_in[13], (const float*)d_in[15], (const float*)d_in[17], (const float*)d_in[19]};
    const float* b2w[4] = {(const float*)d_in[20], (const float*)d_in[22], (const float*)d_in[24], (const float*)d_in[26]};
    const float* b2b[4] = {(const float*)d_in[21], (const float*)d_in[23], (const float*)d_in[25], (const float*)d_in[27]};
    const float* bn1_g  = (const float*)d_in[28];
    const float* bn1_b  = (const float*)d_in[29];
    const float* bn2_g  = (const float*)d_in[30];
    const float* bn2_b  = (const float*)d_in[31];
    const float* dec1_w = (const float*)d_in[32];
    const float* dec1_b = (const float*)d_in[33];
    const float* dec2_w = (const float*)d_in[34];
    const float* dec2_b = (const float*)d_in[35];
    float* out = (float*)d_out;

    char* ws = (char*)d_ws;
    float*          buf0 = (float*)(ws);                    // 33.5 MB fp32: enc out / conv2 out
    float*          buf2 = (float*)(ws + 33554432);         // 33.5 MB fp32: conv1 out
    unsigned short* ybf  = (unsigned short*)(ws + 67108864);// 16.8 MB bf16 channel-last y1/y2
    float*          Bc   = (float*)(ws + 83886080);         // 16.8 MB
    float*          Sini = (float*)(ws + 100663296);        // 16.8 MB
    unsigned short* wprep= (unsigned short*)(ws + 117440512); // 1.67 MB
    float*          sp   = (float*)(ws + 119537664);
    float* sc1 = sp;            // 256
    float* sh1 = sp + 256;      // 256
    float* sc2 = sp + 512;      // 1024
    float* sh2 = sp + 1536;     // 1024
    float* x3l = sp + 2560;     // 16384
    float* Sfin= sp + 18944;    // 1,048,576 floats

    // weight prep (all 8 convs)
    prep_w<<<dim3(768, 8), 256, 0, stream>>>(b1w[0], b1w[1], b1w[2], b1w[3],
                                             b2w[0], b2w[1], b2w[2], b2w[3], wprep);
    // encoder
    enc_kernel<<<8192, 256, 0, stream>>>(x, enc_w, enc_b, buf0);

    // s4a: H=64, L=8192, T=128, NCH=64 ; u=buf0 -> ybf (bf16 [16][8192][64])
    s4_pass1<<<(64*16*64)/64, 64, 0, stream>>>(buf0, nullptr, nullptr, s4a_ldt, Bc, 64, 8192, 128, 64);
    s4_mid  <<<(64*16*32)/64, 64, 0, stream>>>(s4a_ldt, Bc, Sini, nullptr, 64, 64);
    s4_pass2<<<(64*16*64)/64, 64, 0, stream>>>(buf0, nullptr, nullptr, s4a_ldt, s4a_C, s4a_D, Sini, ybf, 64, 8192, 128, 64, 6);

    // conv block1: ybf -> buf2 [256][16][2048] fp32
    dim3 g1(32, 16, 1);
    conv_mfma<64, 1, false><<<g1, 256, 0, stream>>>(ybf, wprep + 0,     b1b[0], buf2, 8192, 2048, 0);
    conv_mfma<64, 2, true ><<<g1, 256, 0, stream>>>(ybf, wprep + 12288, b1b[1], buf2, 8192, 2048, 64);
    conv_mfma<64, 4, true ><<<g1, 256, 0, stream>>>(ybf, wprep + 24576, b1b[2], buf2, 8192, 2048, 128);
    conv_mfma<64, 8, true ><<<g1, 256, 0, stream>>>(ybf, wprep + 36864, b1b[3], buf2, 8192, 2048, 192);
    bn_stats<<<256, 256, 0, stream>>>(buf2, bn1_g, bn1_b, sc1, sh1, 16*2048, 63);

    // s4b: H=256, L=2048, T=128, NCH=16 ; u=BN(buf2) -> ybf (bf16 [16][2048][256])
    s4_pass1<<<(256*16*16)/64, 64, 0, stream>>>(buf2, sc1, sh1, s4b_ldt, Bc, 256, 2048, 128, 16);
    s4_mid  <<<(256*16*32)/64, 64, 0, stream>>>(s4b_ldt, Bc, Sini, nullptr, 256, 16);
    s4_pass2<<<(256*16*16)/64, 64, 0, stream>>>(buf2, sc1, sh1, s4b_ldt, s4b_C, s4b_D, Sini, ybf, 256, 2048, 128, 16, 8);

    // conv block2: ybf -> buf0 [1024][16][512] fp32
    dim3 g2(8, 16, 4);
    conv_mfma<256, 1, false><<<g2, 256, 0, stream>>>(ybf, wprep + 49152,  b2b[0], buf0, 2048, 512, 0);
    conv_mfma<256, 2, true ><<<g2, 256, 0, stream>>>(ybf, wprep + 245760, b2b[1], buf0, 2048, 512, 256);
    conv_mfma<256, 4, true ><<<g2, 256, 0, stream>>>(ybf, wprep + 442368, b2b[2], buf0, 2048, 512, 512);
    conv_mfma<256, 8, true ><<<g2, 256, 0, stream>>>(ybf, wprep + 638976, b2b[3], buf0, 2048, 512, 768);
    bn_stats<<<1024, 256, 0, stream>>>(buf0, bn2_g, bn2_b, sc2, sh2, 16*512, 255);

    // s4c: H=1024, L=512, T=128, NCH=4 ; only final state needed
    s4_pass1<<<(1024*16*4)/64, 64, 0, stream>>>(buf0, sc2, sh2, s4c_ldt, Bc, 1024, 512, 128, 4);
    s4_mid  <<<(1024*16*32)/64, 64, 0, stream>>>(s4c_ldt, Bc, Sini, Sfin, 1024, 4);
    s4c_last<<<16384/256, 256, 0, stream>>>(Sfin, buf0, sc2, sh2, s4c_ldt, s4c_C, s4c_D, x3l);

    // decoder head
    dec_kernel<<<16, 256, 0, stream>>>(x3l, dec1_w, dec1_b, dec2_w, dec2_b, out);
}

// Round 3
// 505.982 us; speedup vs baseline: 2.4402x; 1.1300x over previous
//
#include <hip/hip_runtime.h>
#include <math.h>

#define PI_F 3.14159265358979323846f

typedef __attribute__((ext_vector_type(8))) short short8;
typedef __attribute__((ext_vector_type(4))) float f32x4;

__device__ __forceinline__ unsigned short f2bf(float f) {
    unsigned int u = __float_as_uint(f);
    unsigned int r = (u + 0x7fffu + ((u >> 16) & 1u)) >> 16;
    return (unsigned short)r;
}
__device__ __forceinline__ float bf2f(unsigned short v) {
    return __uint_as_float((unsigned int)v << 16);
}

// ---------------- encoder: x[16][8192][2] -> u1 bf16 [64][16][8192] ----------------
__global__ __launch_bounds__(256) void enc_kernel(
    const float* __restrict__ x, const float* __restrict__ ew,
    const float* __restrict__ eb, unsigned short* __restrict__ u1)
{
    int idx = blockIdx.x * 256 + threadIdx.x;   // 64*16*2048 threads, 4 t each
    int t4 = idx & 2047;
    int b  = (idx >> 11) & 15;
    int h  = idx >> 15;
    float w0 = ew[2*h], w1 = ew[2*h+1], bb = eb[h];
    const float* xp = x + ((size_t)b*8192 + (size_t)t4*4)*2;
    float4 a = *(const float4*)xp;
    float4 c = *(const float4*)(xp + 4);
    ushort4 o;
    o.x = f2bf(fmaf(w0, a.x, fmaf(w1, a.y, bb)));
    o.y = f2bf(fmaf(w0, a.z, fmaf(w1, a.w, bb)));
    o.z = f2bf(fmaf(w0, c.x, fmaf(w1, c.y, bb)));
    o.w = f2bf(fmaf(w0, c.z, fmaf(w1, c.w, bb)));
    *(ushort4*)(u1 + ((size_t)h*16 + b)*8192 + (size_t)t4*4) = o;
}

// ---------------- conv weight prep: fp32 [O][Cin][3] -> bf16 A-frag [kb][o][kk] ------
__global__ __launch_bounds__(256) void prep_w(
    const float* __restrict__ w0, const float* __restrict__ w1,
    const float* __restrict__ w2, const float* __restrict__ w3,
    const float* __restrict__ w4, const float* __restrict__ w5,
    const float* __restrict__ w6, const float* __restrict__ w7,
    unsigned short* __restrict__ wprep)
{
    int id = blockIdx.y;
    const float* src; int Cin; size_t doff;
    switch (id) {
        case 0: src = w0; Cin = 64;  doff = 0;      break;
        case 1: src = w1; Cin = 64;  doff = 12288;  break;
        case 2: src = w2; Cin = 64;  doff = 24576;  break;
        case 3: src = w3; Cin = 64;  doff = 36864;  break;
        case 4: src = w4; Cin = 256; doff = 49152;  break;
        case 5: src = w5; Cin = 256; doff = 245760; break;
        case 6: src = w6; Cin = 256; doff = 442368; break;
        default: src = w7; Cin = 256; doff = 638976; break;
    }
    int e = blockIdx.x * 256 + threadIdx.x;
    if (e >= Cin * Cin * 3) return;
    int kb  = e / (Cin * 32);
    int rem = e - kb * (Cin * 32);
    int o   = rem >> 5;
    int kk  = rem & 31;
    int cch = kb / 6, t6 = kb % 6, k = t6 >> 1, chalf = t6 & 1;
    int c = cch * 64 + chalf * 32 + kk;
    wprep[doff + e] = f2bf(src[((size_t)o * Cin + c) * 3 + k]);
}

// ---------------- S4 prep: build per-h MFMA A-matrices ----------------
// TA[h][kb(6)][m(128)][kk(32)]: cols 0..127 Toeplitz K'[m-col], cols 128..191 W[m][j]
// VA[h][kb(4)][m(64)][kk(32)]: V[2n+ri][s] = w^(127-s) parts
// rs[h][128]: prefix sums of K' (for BN shift); Vrs[h][64]: rowsum of V
__global__ __launch_bounds__(128) void prep_s4(
    const float* __restrict__ log_dt, const float* __restrict__ C2,
    const float* __restrict__ Dv,
    unsigned short* __restrict__ TA, unsigned short* __restrict__ VA,
    float* __restrict__ rs, float* __restrict__ Vrs)
{
    int h = blockIdx.x, t = threadIdx.x;
    __shared__ float cn[64];
    __shared__ float sK[128];
    float dt = expf(log_dt[h]);
    if (t < 32) {
        int n = t;
        float e = expf(-0.5f*dt);
        float s_, c_; sincosf(PI_F*dt*n, &s_, &c_);
        float wr = e*c_, wi = e*s_;
        float ar = -0.5f, ai = PI_F*n;
        float den = 1.f/(ar*ar + ai*ai);
        float tr = wr - 1.f, ti = wi;
        float qr = (tr*ar + ti*ai)*den;
        float qi = (ti*ar - tr*ai)*den;
        float c2r = C2[((size_t)h*32+n)*2], c2i = C2[((size_t)h*32+n)*2+1];
        cn[2*n]   = 2.f*(c2r*qr - c2i*qi);
        cn[2*n+1] = 2.f*(c2r*qi + c2i*qr);
        // Vrs = sum_{j=0}^{127} w^j = (1 - w^128)/(1 - w)
        float e128 = expf(-64.f*dt);
        float s2, c2v; sincosf(PI_F*dt*n*128.f, &s2, &c2v);
        float pr = 1.f - e128*c2v, pim = -e128*s2;
        float dr = 1.f - wr, di = -wi;
        float dd = 1.f/(dr*dr + di*di);
        Vrs[(size_t)h*64 + 2*n]   = (pr*dr + pim*di)*dd;
        Vrs[(size_t)h*64 + 2*n+1] = (pim*dr - pr*di)*dd;
    }
    __syncthreads();
    // thread t: powers w^t -> K[t], V column (s = 127-t), W row (t-1)
    {
        float em = expf(-0.5f*dt*t);
        float Kt = 0.f;
        int colV = 127 - t; int kbV = colV >> 5, kkV = colV & 31;
        for (int n = 0; n < 32; n++) {
            float s_, c_; sincosf(PI_F*dt*(float)(n*t), &s_, &c_);
            float Rw = em*c_, Iw = em*s_;
            float cr = cn[2*n], ci = cn[2*n+1];
            Kt += cr*Rw - ci*Iw;
            VA[(((size_t)h*4 + kbV)*64 + 2*n)*32 + kkV]   = f2bf(Rw);
            VA[(((size_t)h*4 + kbV)*64 + 2*n+1)*32 + kkV] = f2bf(Iw);
            if (t >= 1) {
                int m = t - 1;
                int j0 = 2*n;
                TA[(((size_t)h*6 + 4 + (j0>>5))*128 + m)*32 + (j0&31)] = f2bf(cr*Rw - ci*Iw);
                int j1 = 2*n+1;
                TA[(((size_t)h*6 + 4 + (j1>>5))*128 + m)*32 + (j1&31)] = f2bf(-(cr*Iw + ci*Rw));
            }
        }
        if (t == 127) {  // W row 127 needs power 128
            float em2 = expf(-0.5f*dt*128.f);
            for (int n = 0; n < 32; n++) {
                float s_, c_; sincosf(PI_F*dt*(float)(n*128), &s_, &c_);
                float Rw = em2*c_, Iw = em2*s_;
                float cr = cn[2*n], ci = cn[2*n+1];
                int j0 = 2*n, j1 = 2*n+1;
                TA[(((size_t)h*6 + 4 + (j0>>5))*128 + 127)*32 + (j0&31)] = f2bf(cr*Rw - ci*Iw);
                TA[(((size_t)h*6 + 4 + (j1>>5))*128 + 127)*32 + (j1&31)] = f2bf(-(cr*Iw + ci*Rw));
            }
        }
        sK[t] = Kt + (t == 0 ? Dv[h] : 0.f);
    }
    __syncthreads();
    // prefix sum for BN shift
    {
        float acc = 0.f;
        for (int tau = 0; tau <= t; tau++) acc += sK[tau];
        rs[(size_t)h*128 + t] = acc;
    }
    // Toeplitz fill: row m = t
    for (int col = 0; col < 128; col++) {
        float v = (col <= t) ? sK[t - col] : 0.f;
        TA[(((size_t)h*6 + (col>>5))*128 + t)*32 + (col&31)] = f2bf(v);
    }
}

// ---------------- S4 pass A (GEMM): chunk end-states E = V @ u ----------------
// one wave per block; grid (N/16, H); Bc[(h*16+b)*NCH + c][64]
template<int NCH, int LOGNCH>
__global__ __launch_bounds__(64) void s4_gemm_a(
    const unsigned short* __restrict__ u, const unsigned short* __restrict__ VA,
    const float* __restrict__ Vrs, const float* __restrict__ sc,
    const float* __restrict__ sh, float* __restrict__ Bc)
{
    const int L = NCH * 128;
    int h = blockIdx.y;
    int lane = threadIdx.x;
    int nl = lane & 15, g = lane >> 4;
    int col = blockIdx.x * 16 + nl;
    int b = col >> LOGNCH, c = col & (NCH - 1);
    const unsigned short* up = u + ((size_t)h*16 + b)*L + c*128;
    f32x4 acc[4];
#pragma unroll
    for (int mt = 0; mt < 4; mt++) acc[mt] = (f32x4){0.f,0.f,0.f,0.f};
#pragma unroll
    for (int kb = 0; kb < 4; kb++) {
        short8 bf = *(const short8*)(up + kb*32 + g*8);
#pragma unroll
        for (int mt = 0; mt < 4; mt++) {
            short8 af = *(const short8*)(VA + (((size_t)h*4 + kb)*64 + mt*16 + nl)*32 + g*8);
            acc[mt] = __builtin_amdgcn_mfma_f32_16x16x32_bf16(af, bf, acc[mt], 0, 0, 0);
        }
    }
    float scv = sc ? sc[h] : 1.f;
    float shv = sh ? sh[h] : 0.f;
    float* bp = Bc + (((size_t)h*16 + b)*NCH + c)*64;
#pragma unroll
    for (int mt = 0; mt < 4; mt++) {
        int j0 = mt*16 + g*4;
        float4 vr = *(const float4*)(Vrs + (size_t)h*64 + j0);
        float4 o;
        o.x = fmaf(scv, acc[mt][0], shv*vr.x);
        o.y = fmaf(scv, acc[mt][1], shv*vr.y);
        o.z = fmaf(scv, acc[mt][2], shv*vr.z);
        o.w = fmaf(scv, acc[mt][3], shv*vr.w);
        *(float4*)(bp + j0) = o;
    }
}

// ---------------- S4 mid: chunk-level scan (w^128 via 7 squarings) ----------------
__global__ __launch_bounds__(64) void s4_mid(
    const float* __restrict__ log_dt, const float* __restrict__ Bc,
    float* __restrict__ Sinit, float* __restrict__ Sfinal,
    int H, int NCH)
{
    int gid = blockIdx.x * 64 + threadIdx.x;   // H*16*32
    int n = gid & 31;
    int tmp = gid >> 5;
    int b = tmp & 15;
    int h = tmp >> 4;
    float dt = expf(log_dt[h]);
    float e = expf(-0.5f * dt);
    float s_, c_; sincosf(PI_F * dt * n, &s_, &c_);
    float wr = e * c_, wi = e * s_;
#pragma unroll
    for (int i = 0; i < 7; i++) { float r = wr*wr - wi*wi; float im = 2.f*wr*wi; wr = r; wi = im; }
    float Sr = 0.f, Si = 0.f;
    size_t base = (((size_t)h*16 + b)*NCH)*64 + 2*n;
    for (int c = 0; c < NCH; c++) {
        float2 v; v.x = Sr; v.y = Si;
        *(float2*)(Sinit + base + (size_t)c*64) = v;
        float2 bc = *(const float2*)(Bc + base + (size_t)c*64);
        float r  = fmaf(wr, Sr, fmaf(-wi, Si, bc.x));
        float im = fmaf(wi, Sr, fmaf( wr, Si, bc.y));
        Sr = r; Si = im;
    }
    if (Sfinal) {
        float2 v; v.x = Sr; v.y = Si;
        *(float2*)(Sfinal + ((size_t)h*16 + b)*64 + 2*n) = v;
    }
}

// ---------------- S4 pass C (GEMM): y = sc*(T'@u) + sh*rs + W@Sinit ----------------
// grid (N/64, H), 256 threads; output bf16 [h][b][t]
template<int NCH, int LOGNCH>
__global__ __launch_bounds__(256) void s4_gemm_c(
    const unsigned short* __restrict__ u, const float* __restrict__ Sini,
    const unsigned short* __restrict__ TA, const float* __restrict__ rs,
    const float* __restrict__ sc, const float* __restrict__ sh,
    unsigned short* __restrict__ yout)
{
    const int L = NCH * 128;
    __shared__ unsigned short s_u[64*200];   // 25600 B
    __shared__ unsigned short s_s[64*72];    // 9216 B
    int h = blockIdx.y;
    int tid = threadIdx.x;
    int lane = tid & 63, wid = tid >> 6;
    int nl = lane & 15, g = lane >> 4;
    int col0 = blockIdx.x * 64;
    // stage u chunk (k = 128) for 64 cols
    for (int i = tid; i < 1024; i += 256) {
        int cl = i >> 4, o = i & 15;
        int col = col0 + cl; int b = col >> LOGNCH, c = col & (NCH - 1);
        *(uint4*)&s_u[cl*200 + o*8] =
            *(const uint4*)&u[((size_t)h*16 + b)*L + c*128 + o*8];
    }
    // stage Sinit (64 j) -> bf16
    for (int i = tid; i < 1024; i += 256) {
        int cl = i >> 4, o = i & 15;
        int col = col0 + cl; int b = col >> LOGNCH, c = col & (NCH - 1);
        float4 v = *(const float4*)&Sini[(((size_t)h*16 + b)*NCH + c)*64 + o*4];
        ushort4 q; q.x = f2bf(v.x); q.y = f2bf(v.y); q.z = f2bf(v.z); q.w = f2bf(v.w);
        *(ushort4*)&s_s[cl*72 + o*4] = q;
    }
    __syncthreads();
    f32x4 accT[2][4], accW[2][4];
#pragma unroll
    for (int a = 0; a < 2; a++)
#pragma unroll
        for (int j = 0; j < 4; j++) { accT[a][j] = (f32x4){0,0,0,0}; accW[a][j] = (f32x4){0,0,0,0}; }
#pragma unroll
    for (int kb = 0; kb < 4; kb++) {
        short8 bfr[4];
#pragma unroll
        for (int j = 0; j < 4; j++)
            bfr[j] = *(const short8*)&s_u[(j*16 + nl)*200 + kb*32 + g*8];
#pragma unroll
        for (int mt2 = 0; mt2 < 2; mt2++) {
            int mtile = wid*2 + mt2;
            short8 af = *(const short8*)&TA[(((size_t)h*6 + kb)*128 + mtile*16 + nl)*32 + g*8];
#pragma unroll
            for (int j = 0; j < 4; j++)
                accT[mt2][j] = __builtin_amdgcn_mfma_f32_16x16x32_bf16(af, bfr[j], accT[mt2][j], 0, 0, 0);
        }
    }
#pragma unroll
    for (int kw = 0; kw < 2; kw++) {
        short8 bfr[4];
#pragma unroll
        for (int j = 0; j < 4; j++)
            bfr[j] = *(const short8*)&s_s[(j*16 + nl)*72 + kw*32 + g*8];
#pragma unroll
        for (int mt2 = 0; mt2 < 2; mt2++) {
            int mtile = wid*2 + mt2;
            short8 af = *(const short8*)&TA[(((size_t)h*6 + 4 + kw)*128 + mtile*16 + nl)*32 + g*8];
#pragma unroll
            for (int j = 0; j < 4; j++)
                accW[mt2][j] = __builtin_amdgcn_mfma_f32_16x16x32_bf16(af, bfr[j], accW[mt2][j], 0, 0, 0);
        }
    }
    float scv = sc ? sc[h] : 1.f;
    float shv = sh ? sh[h] : 0.f;
#pragma unroll
    for (int mt2 = 0; mt2 < 2; mt2++) {
        int m0 = (wid*2 + mt2)*16 + g*4;
        float4 rsv = *(const float4*)&rs[(size_t)h*128 + m0];
#pragma unroll
        for (int j = 0; j < 4; j++) {
            int col = col0 + j*16 + nl; int b = col >> LOGNCH, c = col & (NCH - 1);
            ushort4 q;
            q.x = f2bf(fmaf(scv, accT[mt2][j][0], shv*rsv.x) + accW[mt2][j][0]);
            q.y = f2bf(fmaf(scv, accT[mt2][j][1], shv*rsv.y) + accW[mt2][j][1]);
            q.z = f2bf(fmaf(scv, accT[mt2][j][2], shv*rsv.z) + accW[mt2][j][2]);
            q.w = f2bf(fmaf(scv, accT[mt2][j][3], shv*rsv.w) + accW[mt2][j][3]);
            *(ushort4*)&yout[((size_t)h*16 + b)*L + c*128 + m0] = q;
        }
    }
}

// ---------------- S4 pass1 (VALU, bf16 in) — used for s4c only ----------------
__global__ __launch_bounds__(64) void s4_pass1(
    const unsigned short* __restrict__ u, const float* __restrict__ sc,
    const float* __restrict__ sh, const float* __restrict__ log_dt,
    float* __restrict__ Bc, int H, int L, int T, int NCH)
{
    int gid = blockIdx.x * 64 + threadIdx.x;
    int c = gid % NCH;
    int tmp = gid / NCH;
    int b = tmp & 15;
    int h = tmp >> 4;
    float dt = expf(log_dt[h]);
    float e = expf(-0.5f * dt);
    float wr[32], wi[32], sr[32], si[32];
#pragma unroll
    for (int n = 0; n < 32; n++) {
        float s_, c_; sincosf(PI_F * dt * n, &s_, &c_);
        wr[n] = e * c_; wi[n] = e * s_; sr[n] = 0.f; si[n] = 0.f;
    }
    const unsigned short* up = u + ((size_t)h*16 + b)*L + (size_t)c*T;
    float scv = sc ? sc[h] : 1.f;
    float shv = sh ? sh[h] : 0.f;
    for (int t8 = 0; t8 < T/8; ++t8) {
        uint4 raw = *(const uint4*)(up + t8*8);
        unsigned short us[8]; *(uint4*)us = raw;
#pragma unroll
        for (int k = 0; k < 8; k++) {
            float uv = fmaf(scv, bf2f(us[k]), shv);
#pragma unroll
            for (int n = 0; n < 32; n++) {
                float s0 = sr[n], s1 = si[n];
                sr[n] = fmaf(wr[n], s0, fmaf(-wi[n], s1, uv));
                si[n] = fmaf(wi[n], s0, wr[n] * s1);
            }
        }
    }
    float* bp = Bc + (((size_t)h*16 + b)*NCH + c)*64;
#pragma unroll
    for (int n = 0; n < 32; n++) {
        float2 v; v.x = sr[n]; v.y = si[n];
        *(float2*)(bp + 2*n) = v;
    }
}

// ---------------- conv via MFMA bf16; input/output [ch][b][t] bf16 ----------------
template<int CIN, int DIL, bool LRELU>
__global__ __launch_bounds__(256) void conv_mfma(
    const unsigned short* __restrict__ u, const unsigned short* __restrict__ wp,
    const float* __restrict__ bias, unsigned short* __restrict__ out,
    int Lin, int Lout, int jch)
{
    __shared__ unsigned short s_in[4*68*72];   // residue-planed [r][q][ch], 39168 B
    int tid = threadIdx.x;
    int lane = tid & 63, wid = tid >> 6;
    int nl = lane & 15, g = lane >> 4;
    int t0 = blockIdx.x * 64;
    int b  = blockIdx.y;
    int og = blockIdx.z * 64;
    const int P0 = t0 * 4 - 8;

    f32x4 acc[4];
#pragma unroll
    for (int f = 0; f < 4; f++) acc[f] = (f32x4){0.f,0.f,0.f,0.f};

    for (int cc0 = 0; cc0 < CIN; cc0 += 64) {
        if (cc0) __syncthreads();
        // stage: 64 ch x 272 p, in-LDS transpose to [r][q][ch]
        for (int i = tid; i < 2176; i += 256) {
            int ch = i & 63, po = i >> 6;          // po in [0,34)
            int p = P0 + po*8;
            const unsigned short* gp = u + ((size_t)(cc0+ch)*16 + b)*Lin;
            unsigned short tmp[8];
            if (p >= 0 && p + 8 <= Lin) {
                *(uint4*)tmp = *(const uint4*)(gp + p);
            } else {
#pragma unroll
                for (int j = 0; j < 8; j++) {
                    int pj = p + j;
                    tmp[j] = ((unsigned)pj < (unsigned)Lin) ? gp[pj] : (unsigned short)0;
                }
            }
#pragma unroll
            for (int j = 0; j < 8; j++) {
                int pl = po*8 + j;                 // 0..271
                s_in[((pl & 3)*68 + (pl >> 2))*72 + ch] = tmp[j];
            }
        }
        __syncthreads();
#pragma unroll
        for (int k = 0; k < 3; ++k) {
            const int off = (k - 1) * DIL + 8;     // 0..16
            const int r = off & 3, s = off >> 2;
#pragma unroll
            for (int chalf = 0; chalf < 2; ++chalf) {
                int kb = (cc0/64)*6 + k*2 + chalf;
                short8 afrag = *(const short8*)&wp[((size_t)kb*CIN + og + wid*16 + nl)*32 + g*8];
#pragma unroll
                for (int f = 0; f < 4; ++f) {
                    int q = f*16 + nl + s;
                    short8 bfrag = *(const short8*)&s_in[(r*68 + q)*72 + chalf*32 + g*8];
                    acc[f] = __builtin_amdgcn_mfma_f32_16x16x32_bf16(afrag, bfrag, acc[f], 0, 0, 0);
                }
            }
        }
    }
#pragma unroll
    for (int f = 0; f < 4; ++f) {
        int t = t0 + f*16 + nl;
#pragma unroll
        for (int r2 = 0; r2 < 4; ++r2) {
            int o = og + wid*16 + g*4 + r2;
            float v = acc[f][r2] + bias[o];
            if (LRELU) v = v >= 0.f ? v : 0.3f*v;
            out[((size_t)(jch + o)*16 + b)*Lout + t] = f2bf(v);
        }
    }
}

// ---------------- BN stats from bf16 [ch][b][t] ----------------
__global__ __launch_bounds__(256) void bn_stats(
    const unsigned short* __restrict__ x, const float* __restrict__ g,
    const float* __restrict__ bb, float* __restrict__ sc, float* __restrict__ sh,
    int n, int gmask)
{
    int ch = blockIdx.x;
    const unsigned short* xp = x + (size_t)ch * n;
    float s1 = 0.f, s2 = 0.f;
    for (int i = threadIdx.x*8; i < n; i += 2048) {
        uint4 raw = *(const uint4*)(xp + i);
        unsigned short us[8]; *(uint4*)us = raw;
#pragma unroll
        for (int j = 0; j < 8; j++) {
            float v = bf2f(us[j]);
            s1 += v; s2 += v*v;
        }
    }
    for (int o = 32; o > 0; o >>= 1) { s1 += __shfl_down(s1, o); s2 += __shfl_down(s2, o); }
    __shared__ float p1[4], p2[4];
    int wid = threadIdx.x >> 6;
    if ((threadIdx.x & 63) == 0) { p1[wid] = s1; p2[wid] = s2; }
    __syncthreads();
    if (threadIdx.x == 0) {
        s1 = p1[0] + p1[1] + p1[2] + p1[3];
        s2 = p2[0] + p2[1] + p2[2] + p2[3];
        float m = s1 / n;
        float var = s2 / n - m*m;
        float rstd = rsqrtf(var + 1e-5f);
        float scale = g[ch & gmask] * rstd;
        sc[ch] = scale;
        sh[ch] = fmaf(-m, scale, bb[ch & gmask]);
    }
}

// ---------------- s4c final-state -> x3[:, :, 511] ----------------
__global__ __launch_bounds__(256) void s4c_last(
    const float* __restrict__ Sfinal, const unsigned short* __restrict__ u3,
    const float* __restrict__ sc, const float* __restrict__ sh,
    const float* __restrict__ log_dt, const float* __restrict__ C2,
    const float* __restrict__ Dv, float* __restrict__ x3last)
{
    int gid = blockIdx.x*256 + threadIdx.x;  // 16*1024
    int h = gid & 1023;
    int b = gid >> 10;
    float dt = expf(log_dt[h]);
    float e = expf(-0.5f * dt);
    const float* sp = Sfinal + ((size_t)h*16 + b)*64;
    float aR = 0.f, aI = 0.f;
#pragma unroll
    for (int n = 0; n < 32; n++) {
        float s_, c_; sincosf(PI_F * dt * n, &s_, &c_);
        float wr = e*c_, wi = e*s_;
        float ar = -0.5f, ai = PI_F * n;
        float den = 1.f / (ar*ar + ai*ai);
        float tr = wr - 1.f, ti = wi;
        float qr = (tr*ar + ti*ai) * den;
        float qi = (ti*ar - tr*ai) * den;
        float c2r = C2[((size_t)h*32 + n)*2], c2i = C2[((size_t)h*32 + n)*2 + 1];
        float crv = c2r*qr - c2i*qi, civ = c2r*qi + c2i*qr;
        aR = fmaf(crv, sp[2*n],   aR);
        aI = fmaf(civ, sp[2*n+1], aI);
    }
    float uv = fmaf(sc[h], bf2f(u3[((size_t)h*16 + b)*512 + 511]), sh[h]);
    x3last[b*1024 + h] = 2.f*(aR - aI) + Dv[h]*uv;
}

// ---------------- decoder head ----------------
__global__ __launch_bounds__(256) void dec_kernel(
    const float* __restrict__ x3last, const float* __restrict__ w1, const float* __restrict__ b1,
    const float* __restrict__ w2, const float* __restrict__ b2, float* __restrict__ out)
{
    __shared__ float xs[1024];
    int b = blockIdx.x, tid = threadIdx.x;
    for (int i = tid; i < 1024; i += 256) xs[i] = x3last[b*1024 + i];
    __syncthreads();
    float z = b1[tid];
    const float* wpt = w1 + (size_t)tid*1024;
    for (int i = 0; i < 1024; i += 4) {
        float4 wv = *(const float4*)(wpt + i);
        z = fmaf(wv.x, xs[i],   z);
        z = fmaf(wv.y, xs[i+1], z);
        z = fmaf(wv.z, xs[i+2], z);
        z = fmaf(wv.w, xs[i+3], z);
    }
    float v = w2[tid] * z;
    for (int o = 32; o > 0; o >>= 1) v += __shfl_down(v, o);
    __shared__ float ps[4];
    if ((tid & 63) == 0) ps[tid >> 6] = v;
    __syncthreads();
    if (tid == 0) out[b] = ps[0] + ps[1] + ps[2] + ps[3] + b2[0];
}

extern "C" void kernel_launch(void* const* d_in, const int* in_sizes, int n_in,
                              void* d_out, int out_size, void* d_ws, size_t ws_size,
                              hipStream_t stream)
{
    const float* x       = (const float*)d_in[0];
    const float* enc_w   = (const float*)d_in[1];
    const float* enc_b   = (const float*)d_in[2];
    const float* s4a_ldt = (const float*)d_in[3];
    const float* s4a_C   = (const float*)d_in[4];
    const float* s4a_D   = (const float*)d_in[5];
    const float* s4b_ldt = (const float*)d_in[6];
    const float* s4b_C   = (const float*)d_in[7];
    const float* s4b_D   = (const float*)d_in[8];
    const float* s4c_ldt = (const float*)d_in[9];
    const float* s4c_C   = (const float*)d_in[10];
    const float* s4c_D   = (const float*)d_in[11];
    const float* b1w[4] = {(const float*)d_in[12], (const float*)d_in[14], (const float*)d_in[16], (const float*)d_in[18]};
    const float* b1b[4] = {(const float*)d_in[13], (const float*)d_in[15], (const float*)d_in[17], (const float*)d_in[19]};
    const float* b2w[4] = {(const float*)d_in[20], (const float*)d_in[22], (const float*)d_in[24], (const float*)d_in[26]};
    const float* b2b[4] = {(const float*)d_in[21], (const float*)d_in[23], (const float*)d_in[25], (const float*)d_in[27]};
    const float* bn1_g  = (const float*)d_in[28];
    const float* bn1_b  = (const float*)d_in[29];
    const float* bn2_g  = (const float*)d_in[30];
    const float* bn2_b  = (const float*)d_in[31];
    const float* dec1_w = (const float*)d_in[32];
    const float* dec1_b = (const float*)d_in[33];
    const float* dec2_w = (const float*)d_in[34];
    const float* dec2_b = (const float*)d_in[35];
    float* out = (float*)d_out;

    char* ws = (char*)d_ws;
    unsigned short* u1    = (unsigned short*)(ws);              // 16.8 MB (also u3)
    unsigned short* u3    = u1;
    unsigned short* ya    = (unsigned short*)(ws + 16777216);   // 16.8 MB (also yb)
    unsigned short* yb    = ya;
    unsigned short* u2    = (unsigned short*)(ws + 33554432);   // 16.8 MB
    float*          Bc    = (float*)(ws + 50331648);            // 16.8 MB
    float*          Sini  = (float*)(ws + 67108864);            // 16.8 MB
    float*          Sfin  = (float*)(ws + 83886080);            // 4.2 MB
    unsigned short* wprep = (unsigned short*)(ws + 88080384);   // 1.67 MB
    unsigned short* TA_a  = (unsigned short*)(ws + 89751552);   // 3.15 MB
    unsigned short* TA_b  = (unsigned short*)(ws + 92897280);   // 12.6 MB
    unsigned short* VA_a  = (unsigned short*)(ws + 105480192);  // 1.05 MB
    unsigned short* VA_b  = (unsigned short*)(ws + 106528768);  // 4.2 MB
    float*          rs_a  = (float*)(ws + 110723072);           // 32 KB
    float*          rs_b  = (float*)(ws + 110755840);           // 128 KB
    float*          Vrs_a = (float*)(ws + 110886912);           // 16 KB
    float*          Vrs_b = (float*)(ws + 110903296);           // 64 KB
    float*          smallp= (float*)(ws + 110968832);
    float* sc1 = smallp;         // 256
    float* sh1 = smallp + 256;   // 256
    float* sc2 = smallp + 512;   // 1024
    float* sh2 = smallp + 1536;  // 1024
    float* x3l = smallp + 2560;  // 16384

    // prep (independent of data path)
    prep_w<<<dim3(768, 8), 256, 0, stream>>>(b1w[0], b1w[1], b1w[2], b1w[3],
                                             b2w[0], b2w[1], b2w[2], b2w[3], wprep);
    prep_s4<<<64, 128, 0, stream>>>(s4a_ldt, s4a_C, s4a_D, TA_a, VA_a, rs_a, Vrs_a);
    prep_s4<<<256, 128, 0, stream>>>(s4b_ldt, s4b_C, s4b_D, TA_b, VA_b, rs_b, Vrs_b);

    // encoder -> u1 bf16
    enc_kernel<<<8192, 256, 0, stream>>>(x, enc_w, enc_b, u1);

    // s4a: H=64, NCH=64 (L=8192)
    s4_gemm_a<64,6><<<dim3(64, 64), 64, 0, stream>>>(u1, VA_a, Vrs_a, nullptr, nullptr, Bc);
    s4_mid<<<512, 64, 0, stream>>>(s4a_ldt, Bc, Sini, nullptr, 64, 64);
    s4_gemm_c<64,6><<<dim3(16, 64), 256, 0, stream>>>(u1, Sini, TA_a, rs_a, nullptr, nullptr, ya);

    // conv block1: ya [64][16][8192] -> u2 [256][16][2048] bf16
    dim3 g1(32, 16, 1);
    conv_mfma<64, 1, false><<<g1, 256, 0, stream>>>(ya, wprep + 0,     b1b[0], u2, 8192, 2048, 0);
    conv_mfma<64, 2, true ><<<g1, 256, 0, stream>>>(ya, wprep + 12288, b1b[1], u2, 8192, 2048, 64);
    conv_mfma<64, 4, true ><<<g1, 256, 0, stream>>>(ya, wprep + 24576, b1b[2], u2, 8192, 2048, 128);
    conv_mfma<64, 8, true ><<<g1, 256, 0, stream>>>(ya, wprep + 36864, b1b[3], u2, 8192, 2048, 192);
    bn_stats<<<256, 256, 0, stream>>>(u2, bn1_g, bn1_b, sc1, sh1, 16*2048, 63);

    // s4b: H=256, NCH=16 (L=2048)
    s4_gemm_a<16,4><<<dim3(16, 256), 64, 0, stream>>>(u2, VA_b, Vrs_b, sc1, sh1, Bc);
    s4_mid<<<2048, 64, 0, stream>>>(s4b_ldt, Bc, Sini, nullptr, 256, 16);
    s4_gemm_c<16,4><<<dim3(4, 256), 256, 0, stream>>>(u2, Sini, TA_b, rs_b, sc1, sh1, yb);

    // conv block2: yb [256][16][2048] -> u3 [1024][16][512] bf16
    dim3 g2(8, 16, 4);
    conv_mfma<256, 1, false><<<g2, 256, 0, stream>>>(yb, wprep + 49152,  b2b[0], u3, 2048, 512, 0);
    conv_mfma<256, 2, true ><<<g2, 256, 0, stream>>>(yb, wprep + 245760, b2b[1], u3, 2048, 512, 256);
    conv_mfma<256, 4, true ><<<g2, 256, 0, stream>>>(yb, wprep + 442368, b2b[2], u3, 2048, 512, 512);
    conv_mfma<256, 8, true ><<<g2, 256, 0, stream>>>(yb, wprep + 638976, b2b[3], u3, 2048, 512, 768);
    bn_stats<<<1024, 256, 0, stream>>>(u3, bn2_g, bn2_b, sc2, sh2, 16*512, 255);

    // s4c: H=1024, NCH=4 (L=512); only final state needed
    s4_pass1<<<1024, 64, 0, stream>>>(u3, sc2, sh2, s4c_ldt, Bc, 1024, 512, 128, 4);
    s4_mid<<<8192, 64, 0, stream>>>(s4c_ldt, Bc, Sini, Sfin, 1024, 4);
    s4c_last<<<64, 256, 0, stream>>>(Sfin, u3, sc2, sh2, s4c_ldt, s4c_C, s4c_D, x3l);

    // decoder head
    dec_kernel<<<16, 256, 0, stream>>>(x3l, dec1_w, dec1_b, dec2_w, dec2_b, out);
}

// Round 4
// 487.439 us; speedup vs baseline: 2.5330x; 1.0380x over previous
//
#include <hip/hip_runtime.h>
#include <math.h>

#define PI_F 3.14159265358979323846f

typedef __attribute__((ext_vector_type(8))) short short8;
typedef __attribute__((ext_vector_type(4))) float f32x4;

__device__ __forceinline__ unsigned short f2bf(float f) {
    unsigned int u = __float_as_uint(f);
    unsigned int r = (u + 0x7fffu + ((u >> 16) & 1u)) >> 16;
    return (unsigned short)r;
}
__device__ __forceinline__ float bf2f(unsigned short v) {
    return __uint_as_float((unsigned int)v << 16);
}

// ---------------- encoder: x[16][8192][2] -> u1 bf16 [64][16][8192] ----------------
__global__ __launch_bounds__(256) void enc_kernel(
    const float* __restrict__ x, const float* __restrict__ ew,
    const float* __restrict__ eb, unsigned short* __restrict__ u1)
{
    int idx = blockIdx.x * 256 + threadIdx.x;   // 64*16*2048 threads, 4 t each
    int t4 = idx & 2047;
    int b  = (idx >> 11) & 15;
    int h  = idx >> 15;
    float w0 = ew[2*h], w1 = ew[2*h+1], bb = eb[h];
    const float* xp = x + ((size_t)b*8192 + (size_t)t4*4)*2;
    float4 a = *(const float4*)xp;
    float4 c = *(const float4*)(xp + 4);
    ushort4 o;
    o.x = f2bf(fmaf(w0, a.x, fmaf(w1, a.y, bb)));
    o.y = f2bf(fmaf(w0, a.z, fmaf(w1, a.w, bb)));
    o.z = f2bf(fmaf(w0, c.x, fmaf(w1, c.y, bb)));
    o.w = f2bf(fmaf(w0, c.z, fmaf(w1, c.w, bb)));
    *(ushort4*)(u1 + ((size_t)h*16 + b)*8192 + (size_t)t4*4) = o;
}

// ---------------- conv weight prep: fp32 [O][Cin][3] -> bf16 A-frag [kb][o][kk] ------
__global__ __launch_bounds__(256) void prep_w(
    const float* __restrict__ w0, const float* __restrict__ w1,
    const float* __restrict__ w2, const float* __restrict__ w3,
    const float* __restrict__ w4, const float* __restrict__ w5,
    const float* __restrict__ w6, const float* __restrict__ w7,
    unsigned short* __restrict__ wprep)
{
    int id = blockIdx.y;
    const float* src; int Cin; size_t doff;
    switch (id) {
        case 0: src = w0; Cin = 64;  doff = 0;      break;
        case 1: src = w1; Cin = 64;  doff = 12288;  break;
        case 2: src = w2; Cin = 64;  doff = 24576;  break;
        case 3: src = w3; Cin = 64;  doff = 36864;  break;
        case 4: src = w4; Cin = 256; doff = 49152;  break;
        case 5: src = w5; Cin = 256; doff = 245760; break;
        case 6: src = w6; Cin = 256; doff = 442368; break;
        default: src = w7; Cin = 256; doff = 638976; break;
    }
    int e = blockIdx.x * 256 + threadIdx.x;
    if (e >= Cin * Cin * 3) return;
    int kb  = e / (Cin * 32);
    int rem = e - kb * (Cin * 32);
    int o   = rem >> 5;
    int kk  = rem & 31;
    int cch = kb / 6, t6 = kb % 6, k = t6 >> 1, chalf = t6 & 1;
    int c = cch * 64 + chalf * 32 + kk;
    wprep[doff + e] = f2bf(src[((size_t)o * Cin + c) * 3 + k]);
}

// ---------------- S4 prep: build per-h MFMA A-matrices ----------------
// TA[h][kb(6)][m(128)][kk(32)]: cols 0..127 Toeplitz K'[m-col], cols 128..191 W[m][j]
// VA[h][kb(4)][m(64)][kk(32)]: V[2n+ri][s] = w^(127-s) parts
// rs[h][128]: prefix sums of K' (for BN shift); Vrs[h][64]: rowsum of V
__global__ __launch_bounds__(128) void prep_s4(
    const float* __restrict__ log_dt, const float* __restrict__ C2,
    const float* __restrict__ Dv,
    unsigned short* __restrict__ TA, unsigned short* __restrict__ VA,
    float* __restrict__ rs, float* __restrict__ Vrs)
{
    int h = blockIdx.x, t = threadIdx.x;
    __shared__ float cn[64];
    __shared__ float sK[128];
    float dt = expf(log_dt[h]);
    if (t < 32) {
        int n = t;
        float e = expf(-0.5f*dt);
        float s_, c_; sincosf(PI_F*dt*n, &s_, &c_);
        float wr = e*c_, wi = e*s_;
        float ar = -0.5f, ai = PI_F*n;
        float den = 1.f/(ar*ar + ai*ai);
        float tr = wr - 1.f, ti = wi;
        float qr = (tr*ar + ti*ai)*den;
        float qi = (ti*ar - tr*ai)*den;
        float c2r = C2[((size_t)h*32+n)*2], c2i = C2[((size_t)h*32+n)*2+1];
        cn[2*n]   = 2.f*(c2r*qr - c2i*qi);
        cn[2*n+1] = 2.f*(c2r*qi + c2i*qr);
        // Vrs = sum_{j=0}^{127} w^j = (1 - w^128)/(1 - w)
        float e128 = expf(-64.f*dt);
        float s2, c2v; sincosf(PI_F*dt*n*128.f, &s2, &c2v);
        float pr = 1.f - e128*c2v, pim = -e128*s2;
        float dr = 1.f - wr, di = -wi;
        float dd = 1.f/(dr*dr + di*di);
        Vrs[(size_t)h*64 + 2*n]   = (pr*dr + pim*di)*dd;
        Vrs[(size_t)h*64 + 2*n+1] = (pim*dr - pr*di)*dd;
    }
    __syncthreads();
    // thread t: powers w^t -> K[t], V column (s = 127-t), W row (t-1)
    {
        float em = expf(-0.5f*dt*t);
        float Kt = 0.f;
        int colV = 127 - t; int kbV = colV >> 5, kkV = colV & 31;
        for (int n = 0; n < 32; n++) {
            float s_, c_; sincosf(PI_F*dt*(float)(n*t), &s_, &c_);
            float Rw = em*c_, Iw = em*s_;
            float cr = cn[2*n], ci = cn[2*n+1];
            Kt += cr*Rw - ci*Iw;
            VA[(((size_t)h*4 + kbV)*64 + 2*n)*32 + kkV]   = f2bf(Rw);
            VA[(((size_t)h*4 + kbV)*64 + 2*n+1)*32 + kkV] = f2bf(Iw);
            if (t >= 1) {
                int m = t - 1;
                int j0 = 2*n;
                TA[(((size_t)h*6 + 4 + (j0>>5))*128 + m)*32 + (j0&31)] = f2bf(cr*Rw - ci*Iw);
                int j1 = 2*n+1;
                TA[(((size_t)h*6 + 4 + (j1>>5))*128 + m)*32 + (j1&31)] = f2bf(-(cr*Iw + ci*Rw));
            }
        }
        if (t == 127) {  // W row 127 needs power 128
            float em2 = expf(-0.5f*dt*128.f);
            for (int n = 0; n < 32; n++) {
                float s_, c_; sincosf(PI_F*dt*(float)(n*128), &s_, &c_);
                float Rw = em2*c_, Iw = em2*s_;
                float cr = cn[2*n], ci = cn[2*n+1];
                int j0 = 2*n, j1 = 2*n+1;
                TA[(((size_t)h*6 + 4 + (j0>>5))*128 + 127)*32 + (j0&31)] = f2bf(cr*Rw - ci*Iw);
                TA[(((size_t)h*6 + 4 + (j1>>5))*128 + 127)*32 + (j1&31)] = f2bf(-(cr*Iw + ci*Rw));
            }
        }
        sK[t] = Kt + (t == 0 ? Dv[h] : 0.f);
    }
    __syncthreads();
    // prefix sum for BN shift
    {
        float acc = 0.f;
        for (int tau = 0; tau <= t; tau++) acc += sK[tau];
        rs[(size_t)h*128 + t] = acc;
    }
    // Toeplitz fill: row m = t
    for (int col = 0; col < 128; col++) {
        float v = (col <= t) ? sK[t - col] : 0.f;
        TA[(((size_t)h*6 + (col>>5))*128 + t)*32 + (col&31)] = f2bf(v);
    }
}

// ---------------- slim prep: V matrix + rowsums only (for s4c) ----------------
__global__ __launch_bounds__(128) void prep_va(
    const float* __restrict__ log_dt,
    unsigned short* __restrict__ VA, float* __restrict__ Vrs)
{
    int h = blockIdx.x, t = threadIdx.x;
    float dt = expf(log_dt[h]);
    float em = expf(-0.5f*dt*t);
    int colV = 127 - t; int kbV = colV >> 5, kkV = colV & 31;
    for (int n = 0; n < 32; n++) {
        float s_, c_; sincosf(PI_F*dt*(float)(n*t), &s_, &c_);
        VA[(((size_t)h*4 + kbV)*64 + 2*n)*32 + kkV]   = f2bf(em*c_);
        VA[(((size_t)h*4 + kbV)*64 + 2*n+1)*32 + kkV] = f2bf(em*s_);
    }
    if (t < 32) {
        int n = t;
        float e = expf(-0.5f*dt);
        float s_, c_; sincosf(PI_F*dt*n, &s_, &c_);
        float wr = e*c_, wi = e*s_;
        float e128 = expf(-64.f*dt);
        float s2, c2v; sincosf(PI_F*dt*n*128.f, &s2, &c2v);
        float pr = 1.f - e128*c2v, pim = -e128*s2;
        float dr = 1.f - wr, di = -wi;
        float dd = 1.f/(dr*dr + di*di);
        Vrs[(size_t)h*64 + 2*n]   = (pr*dr + pim*di)*dd;
        Vrs[(size_t)h*64 + 2*n+1] = (pim*dr - pr*di)*dd;
    }
}

// ---------------- S4 pass A (GEMM): chunk end-states E = V @ u ----------------
// one wave per block; grid (N/16, H); Bc[(h*16+b)*NCH + c][64]
template<int NCH, int LOGNCH>
__global__ __launch_bounds__(64) void s4_gemm_a(
    const unsigned short* __restrict__ u, const unsigned short* __restrict__ VA,
    const float* __restrict__ Vrs, const float* __restrict__ sc,
    const float* __restrict__ sh, float* __restrict__ Bc)
{
    const int L = NCH * 128;
    int h = blockIdx.y;
    int lane = threadIdx.x;
    int nl = lane & 15, g = lane >> 4;
    int col = blockIdx.x * 16 + nl;
    int b = col >> LOGNCH, c = col & (NCH - 1);
    const unsigned short* up = u + ((size_t)h*16 + b)*L + c*128;
    f32x4 acc[4];
#pragma unroll
    for (int mt = 0; mt < 4; mt++) acc[mt] = (f32x4){0.f,0.f,0.f,0.f};
#pragma unroll
    for (int kb = 0; kb < 4; kb++) {
        short8 bf = *(const short8*)(up + kb*32 + g*8);
#pragma unroll
        for (int mt = 0; mt < 4; mt++) {
            short8 af = *(const short8*)(VA + (((size_t)h*4 + kb)*64 + mt*16 + nl)*32 + g*8);
            acc[mt] = __builtin_amdgcn_mfma_f32_16x16x32_bf16(af, bf, acc[mt], 0, 0, 0);
        }
    }
    float scv = sc ? sc[h] : 1.f;
    float shv = sh ? sh[h] : 0.f;
    float* bp = Bc + (((size_t)h*16 + b)*NCH + c)*64;
#pragma unroll
    for (int mt = 0; mt < 4; mt++) {
        int j0 = mt*16 + g*4;
        float4 vr = *(const float4*)(Vrs + (size_t)h*64 + j0);
        float4 o;
        o.x = fmaf(scv, acc[mt][0], shv*vr.x);
        o.y = fmaf(scv, acc[mt][1], shv*vr.y);
        o.z = fmaf(scv, acc[mt][2], shv*vr.z);
        o.w = fmaf(scv, acc[mt][3], shv*vr.w);
        *(float4*)(bp + j0) = o;
    }
}

// ---------------- S4 mid: chunk-level scan (w^128 via 7 squarings) ----------------
__global__ __launch_bounds__(64) void s4_mid(
    const float* __restrict__ log_dt, const float* __restrict__ Bc,
    float* __restrict__ Sinit, float* __restrict__ Sfinal,
    int H, int NCH)
{
    int gid = blockIdx.x * 64 + threadIdx.x;   // H*16*32
    int n = gid & 31;
    int tmp = gid >> 5;
    int b = tmp & 15;
    int h = tmp >> 4;
    float dt = expf(log_dt[h]);
    float e = expf(-0.5f * dt);
    float s_, c_; sincosf(PI_F * dt * n, &s_, &c_);
    float wr = e * c_, wi = e * s_;
#pragma unroll
    for (int i = 0; i < 7; i++) { float r = wr*wr - wi*wi; float im = 2.f*wr*wi; wr = r; wi = im; }
    float Sr = 0.f, Si = 0.f;
    size_t base = (((size_t)h*16 + b)*NCH)*64 + 2*n;
    for (int c = 0; c < NCH; c++) {
        float2 v; v.x = Sr; v.y = Si;
        *(float2*)(Sinit + base + (size_t)c*64) = v;
        float2 bc = *(const float2*)(Bc + base + (size_t)c*64);
        float r  = fmaf(wr, Sr, fmaf(-wi, Si, bc.x));
        float im = fmaf(wi, Sr, fmaf( wr, Si, bc.y));
        Sr = r; Si = im;
    }
    if (Sfinal) {
        float2 v; v.x = Sr; v.y = Si;
        *(float2*)(Sfinal + ((size_t)h*16 + b)*64 + 2*n) = v;
    }
}

// ---------------- S4 pass C (GEMM): y = sc*(T'@u) + sh*rs + W@Sinit ----------------
// grid (N/64, H), 256 threads; output bf16 [h][b][t]
template<int NCH, int LOGNCH>
__global__ __launch_bounds__(256) void s4_gemm_c(
    const unsigned short* __restrict__ u, const float* __restrict__ Sini,
    const unsigned short* __restrict__ TA, const float* __restrict__ rs,
    const float* __restrict__ sc, const float* __restrict__ sh,
    unsigned short* __restrict__ yout)
{
    const int L = NCH * 128;
    __shared__ unsigned short s_u[64*200];   // 25600 B
    __shared__ unsigned short s_s[64*72];    // 9216 B
    int h = blockIdx.y;
    int tid = threadIdx.x;
    int lane = tid & 63, wid = tid >> 6;
    int nl = lane & 15, g = lane >> 4;
    int col0 = blockIdx.x * 64;
    // stage u chunk (k = 128) for 64 cols
    for (int i = tid; i < 1024; i += 256) {
        int cl = i >> 4, o = i & 15;
        int col = col0 + cl; int b = col >> LOGNCH, c = col & (NCH - 1);
        *(uint4*)&s_u[cl*200 + o*8] =
            *(const uint4*)&u[((size_t)h*16 + b)*L + c*128 + o*8];
    }
    // stage Sinit (64 j) -> bf16
    for (int i = tid; i < 1024; i += 256) {
        int cl = i >> 4, o = i & 15;
        int col = col0 + cl; int b = col >> LOGNCH, c = col & (NCH - 1);
        float4 v = *(const float4*)&Sini[(((size_t)h*16 + b)*NCH + c)*64 + o*4];
        ushort4 q; q.x = f2bf(v.x); q.y = f2bf(v.y); q.z = f2bf(v.z); q.w = f2bf(v.w);
        *(ushort4*)&s_s[cl*72 + o*4] = q;
    }
    __syncthreads();
    f32x4 accT[2][4], accW[2][4];
#pragma unroll
    for (int a = 0; a < 2; a++)
#pragma unroll
        for (int j = 0; j < 4; j++) { accT[a][j] = (f32x4){0,0,0,0}; accW[a][j] = (f32x4){0,0,0,0}; }
#pragma unroll
    for (int kb = 0; kb < 4; kb++) {
        short8 bfr[4];
#pragma unroll
        for (int j = 0; j < 4; j++)
            bfr[j] = *(const short8*)&s_u[(j*16 + nl)*200 + kb*32 + g*8];
#pragma unroll
        for (int mt2 = 0; mt2 < 2; mt2++) {
            int mtile = wid*2 + mt2;
            short8 af = *(const short8*)&TA[(((size_t)h*6 + kb)*128 + mtile*16 + nl)*32 + g*8];
#pragma unroll
            for (int j = 0; j < 4; j++)
                accT[mt2][j] = __builtin_amdgcn_mfma_f32_16x16x32_bf16(af, bfr[j], accT[mt2][j], 0, 0, 0);
        }
    }
#pragma unroll
    for (int kw = 0; kw < 2; kw++) {
        short8 bfr[4];
#pragma unroll
        for (int j = 0; j < 4; j++)
            bfr[j] = *(const short8*)&s_s[(j*16 + nl)*72 + kw*32 + g*8];
#pragma unroll
        for (int mt2 = 0; mt2 < 2; mt2++) {
            int mtile = wid*2 + mt2;
            short8 af = *(const short8*)&TA[(((size_t)h*6 + 4 + kw)*128 + mtile*16 + nl)*32 + g*8];
#pragma unroll
            for (int j = 0; j < 4; j++)
                accW[mt2][j] = __builtin_amdgcn_mfma_f32_16x16x32_bf16(af, bfr[j], accW[mt2][j], 0, 0, 0);
        }
    }
    float scv = sc ? sc[h] : 1.f;
    float shv = sh ? sh[h] : 0.f;
#pragma unroll
    for (int mt2 = 0; mt2 < 2; mt2++) {
        int m0 = (wid*2 + mt2)*16 + g*4;
        float4 rsv = *(const float4*)&rs[(size_t)h*128 + m0];
#pragma unroll
        for (int j = 0; j < 4; j++) {
            int col = col0 + j*16 + nl; int b = col >> LOGNCH, c = col & (NCH - 1);
            ushort4 q;
            q.x = f2bf(fmaf(scv, accT[mt2][j][0], shv*rsv.x) + accW[mt2][j][0]);
            q.y = f2bf(fmaf(scv, accT[mt2][j][1], shv*rsv.y) + accW[mt2][j][1]);
            q.z = f2bf(fmaf(scv, accT[mt2][j][2], shv*rsv.z) + accW[mt2][j][2]);
            q.w = f2bf(fmaf(scv, accT[mt2][j][3], shv*rsv.w) + accW[mt2][j][3]);
            *(ushort4*)&yout[((size_t)h*16 + b)*L + c*128 + m0] = q;
        }
    }
}

// ---------------- conv via MFMA bf16; input/output [ch][b][t] bf16 ----------------
template<int CIN, int DIL, bool LRELU>
__global__ __launch_bounds__(256) void conv_mfma(
    const unsigned short* __restrict__ u, const unsigned short* __restrict__ wp,
    const float* __restrict__ bias, unsigned short* __restrict__ out,
    int Lin, int Lout, int jch)
{
    __shared__ unsigned short s_in[4*68*72];   // residue-planed [r][q][ch], 39168 B
    int tid = threadIdx.x;
    int lane = tid & 63, wid = tid >> 6;
    int nl = lane & 15, g = lane >> 4;
    int t0 = blockIdx.x * 64;
    int b  = blockIdx.y;
    int og = blockIdx.z * 64;
    const int P0 = t0 * 4 - 8;

    f32x4 acc[4];
#pragma unroll
    for (int f = 0; f < 4; f++) acc[f] = (f32x4){0.f,0.f,0.f,0.f};

    for (int cc0 = 0; cc0 < CIN; cc0 += 64) {
        if (cc0) __syncthreads();
        // stage: 64 ch x 272 p, in-LDS transpose to [r][q][ch]
        for (int i = tid; i < 2176; i += 256) {
            int ch = i & 63, po = i >> 6;          // po in [0,34)
            int p = P0 + po*8;
            const unsigned short* gp = u + ((size_t)(cc0+ch)*16 + b)*Lin;
            unsigned short tmp[8];
            if (p >= 0 && p + 8 <= Lin) {
                *(uint4*)tmp = *(const uint4*)(gp + p);
            } else {
#pragma unroll
                for (int j = 0; j < 8; j++) {
                    int pj = p + j;
                    tmp[j] = ((unsigned)pj < (unsigned)Lin) ? gp[pj] : (unsigned short)0;
                }
            }
#pragma unroll
            for (int j = 0; j < 8; j++) {
                int pl = po*8 + j;                 // 0..271
                s_in[((pl & 3)*68 + (pl >> 2))*72 + ch] = tmp[j];
            }
        }
        __syncthreads();
#pragma unroll
        for (int k = 0; k < 3; ++k) {
            const int off = (k - 1) * DIL + 8;     // 0..16
            const int r = off & 3, s = off >> 2;
#pragma unroll
            for (int chalf = 0; chalf < 2; ++chalf) {
                int kb = (cc0/64)*6 + k*2 + chalf;
                short8 afrag = *(const short8*)&wp[((size_t)kb*CIN + og + wid*16 + nl)*32 + g*8];
#pragma unroll
                for (int f = 0; f < 4; ++f) {
                    int q = f*16 + nl + s;
                    short8 bfrag = *(const short8*)&s_in[(r*68 + q)*72 + chalf*32 + g*8];
                    acc[f] = __builtin_amdgcn_mfma_f32_16x16x32_bf16(afrag, bfrag, acc[f], 0, 0, 0);
                }
            }
        }
    }
#pragma unroll
    for (int f = 0; f < 4; ++f) {
        int t = t0 + f*16 + nl;
#pragma unroll
        for (int r2 = 0; r2 < 4; ++r2) {
            int o = og + wid*16 + g*4 + r2;
            float v = acc[f][r2] + bias[o];
            if (LRELU) v = v >= 0.f ? v : 0.3f*v;
            out[((size_t)(jch + o)*16 + b)*Lout + t] = f2bf(v);
        }
    }
}

// ---------------- BN stats from bf16 [ch][b][t] ----------------
__global__ __launch_bounds__(256) void bn_stats(
    const unsigned short* __restrict__ x, const float* __restrict__ g,
    const float* __restrict__ bb, float* __restrict__ sc, float* __restrict__ sh,
    int n, int gmask)
{
    int ch = blockIdx.x;
    const unsigned short* xp = x + (size_t)ch * n;
    float s1 = 0.f, s2 = 0.f;
    for (int i = threadIdx.x*8; i < n; i += 2048) {
        uint4 raw = *(const uint4*)(xp + i);
        unsigned short us[8]; *(uint4*)us = raw;
#pragma unroll
        for (int j = 0; j < 8; j++) {
            float v = bf2f(us[j]);
            s1 += v; s2 += v*v;
        }
    }
    for (int o = 32; o > 0; o >>= 1) { s1 += __shfl_down(s1, o); s2 += __shfl_down(s2, o); }
    __shared__ float p1[4], p2[4];
    int wid = threadIdx.x >> 6;
    if ((threadIdx.x & 63) == 0) { p1[wid] = s1; p2[wid] = s2; }
    __syncthreads();
    if (threadIdx.x == 0) {
        s1 = p1[0] + p1[1] + p1[2] + p1[3];
        s2 = p2[0] + p2[1] + p2[2] + p2[3];
        float m = s1 / n;
        float var = s2 / n - m*m;
        float rstd = rsqrtf(var + 1e-5f);
        float scale = g[ch & gmask] * rstd;
        sc[ch] = scale;
        sh[ch] = fmaf(-m, scale, bb[ch & gmask]);
    }
}

// ---------------- s4c final-state -> x3[:, :, 511] ----------------
__global__ __launch_bounds__(256) void s4c_last(
    const float* __restrict__ Sfinal, const unsigned short* __restrict__ u3,
    const float* __restrict__ sc, const float* __restrict__ sh,
    const float* __restrict__ log_dt, const float* __restrict__ C2,
    const float* __restrict__ Dv, float* __restrict__ x3last)
{
    int gid = blockIdx.x*256 + threadIdx.x;  // 16*1024
    int h = gid & 1023;
    int b = gid >> 10;
    float dt = expf(log_dt[h]);
    float e = expf(-0.5f * dt);
    const float* sp = Sfinal + ((size_t)h*16 + b)*64;
    float aR = 0.f, aI = 0.f;
#pragma unroll
    for (int n = 0; n < 32; n++) {
        float s_, c_; sincosf(PI_F * dt * n, &s_, &c_);
        float wr = e*c_, wi = e*s_;
        float ar = -0.5f, ai = PI_F * n;
        float den = 1.f / (ar*ar + ai*ai);
        float tr = wr - 1.f, ti = wi;
        float qr = (tr*ar + ti*ai) * den;
        float qi = (ti*ar - tr*ai) * den;
        float c2r = C2[((size_t)h*32 + n)*2], c2i = C2[((size_t)h*32 + n)*2 + 1];
        float crv = c2r*qr - c2i*qi, civ = c2r*qi + c2i*qr;
        aR = fmaf(crv, sp[2*n],   aR);
        aI = fmaf(civ, sp[2*n+1], aI);
    }
    float uv = fmaf(sc[h], bf2f(u3[((size_t)h*16 + b)*512 + 511]), sh[h]);
    x3last[b*1024 + h] = 2.f*(aR - aI) + Dv[h]*uv;
}

// ---------------- decoder head ----------------
__global__ __launch_bounds__(256) void dec_kernel(
    const float* __restrict__ x3last, const float* __restrict__ w1, const float* __restrict__ b1,
    const float* __restrict__ w2, const float* __restrict__ b2, float* __restrict__ out)
{
    __shared__ float xs[1024];
    int b = blockIdx.x, tid = threadIdx.x;
    for (int i = tid; i < 1024; i += 256) xs[i] = x3last[b*1024 + i];
    __syncthreads();
    float z = b1[tid];
    const float* wpt = w1 + (size_t)tid*1024;
    for (int i = 0; i < 1024; i += 4) {
        float4 wv = *(const float4*)(wpt + i);
        z = fmaf(wv.x, xs[i],   z);
        z = fmaf(wv.y, xs[i+1], z);
        z = fmaf(wv.z, xs[i+2], z);
        z = fmaf(wv.w, xs[i+3], z);
    }
    float v = w2[tid] * z;
    for (int o = 32; o > 0; o >>= 1) v += __shfl_down(v, o);
    __shared__ float ps[4];
    if ((tid & 63) == 0) ps[tid >> 6] = v;
    __syncthreads();
    if (tid == 0) out[b] = ps[0] + ps[1] + ps[2] + ps[3] + b2[0];
}

extern "C" void kernel_launch(void* const* d_in, const int* in_sizes, int n_in,
                              void* d_out, int out_size, void* d_ws, size_t ws_size,
                              hipStream_t stream)
{
    const float* x       = (const float*)d_in[0];
    const float* enc_w   = (const float*)d_in[1];
    const float* enc_b   = (const float*)d_in[2];
    const float* s4a_ldt = (const float*)d_in[3];
    const float* s4a_C   = (const float*)d_in[4];
    const float* s4a_D   = (const float*)d_in[5];
    const float* s4b_ldt = (const float*)d_in[6];
    const float* s4b_C   = (const float*)d_in[7];
    const float* s4b_D   = (const float*)d_in[8];
    const float* s4c_ldt = (const float*)d_in[9];
    const float* s4c_C   = (const float*)d_in[10];
    const float* s4c_D   = (const float*)d_in[11];
    const float* b1w[4] = {(const float*)d_in[12], (const float*)d_in[14], (const float*)d_in[16], (const float*)d_in[18]};
    const float* b1b[4] = {(const float*)d_in[13], (const float*)d_in[15], (const float*)d_in[17], (const float*)d_in[19]};
    const float* b2w[4] = {(const float*)d_in[20], (const float*)d_in[22], (const float*)d_in[24], (const float*)d_in[26]};
    const float* b2b[4] = {(const float*)d_in[21], (const float*)d_in[23], (const float*)d_in[25], (const float*)d_in[27]};
    const float* bn1_g  = (const float*)d_in[28];
    const float* bn1_b  = (const float*)d_in[29];
    const float* bn2_g  = (const float*)d_in[30];
    const float* bn2_b  = (const float*)d_in[31];
    const float* dec1_w = (const float*)d_in[32];
    const float* dec1_b = (const float*)d_in[33];
    const float* dec2_w = (const float*)d_in[34];
    const float* dec2_b = (const float*)d_in[35];
    float* out = (float*)d_out;

    char* ws = (char*)d_ws;
    unsigned short* u1    = (unsigned short*)(ws);              // 16.8 MB (also u3)
    unsigned short* u3    = u1;
    unsigned short* ya    = (unsigned short*)(ws + 16777216);   // 16.8 MB (also yb, later VA_c)
    unsigned short* yb    = ya;
    unsigned short* VA_c  = ya;                                 // reuse after conv2
    unsigned short* u2    = (unsigned short*)(ws + 33554432);   // 16.8 MB
    float*          Bc    = (float*)(ws + 50331648);            // 16.8 MB
    float*          Sini  = (float*)(ws + 67108864);            // 16.8 MB
    float*          Sfin  = (float*)(ws + 83886080);            // 4.2 MB
    unsigned short* wprep = (unsigned short*)(ws + 88080384);   // 1.67 MB
    unsigned short* TA_a  = (unsigned short*)(ws + 89751552);   // 3.15 MB
    unsigned short* TA_b  = (unsigned short*)(ws + 92897280);   // 12.6 MB
    unsigned short* VA_a  = (unsigned short*)(ws + 105480192);  // 1.05 MB
    unsigned short* VA_b  = (unsigned short*)(ws + 106528768);  // 4.2 MB
    float*          rs_a  = (float*)(ws + 110723072);           // 32 KB
    float*          rs_b  = (float*)(ws + 110755840);           // 128 KB
    float*          Vrs_a = (float*)(ws + 110886912);           // 16 KB
    float*          Vrs_b = (float*)(ws + 110903296);           // 64 KB
    float*          smallp= (float*)(ws + 110968832);
    float* sc1 = smallp;         // 256
    float* sh1 = smallp + 256;   // 256
    float* sc2 = smallp + 512;   // 1024
    float* sh2 = smallp + 1536;  // 1024
    float* x3l = smallp + 2560;  // 16384
    float*          Vrs_c = (float*)(ws + 111280128);           // 256 KB

    // prep (independent of data path)
    prep_w<<<dim3(768, 8), 256, 0, stream>>>(b1w[0], b1w[1], b1w[2], b1w[3],
                                             b2w[0], b2w[1], b2w[2], b2w[3], wprep);
    prep_s4<<<64, 128, 0, stream>>>(s4a_ldt, s4a_C, s4a_D, TA_a, VA_a, rs_a, Vrs_a);
    prep_s4<<<256, 128, 0, stream>>>(s4b_ldt, s4b_C, s4b_D, TA_b, VA_b, rs_b, Vrs_b);

    // encoder -> u1 bf16
    enc_kernel<<<8192, 256, 0, stream>>>(x, enc_w, enc_b, u1);

    // s4a: H=64, NCH=64 (L=8192)
    s4_gemm_a<64,6><<<dim3(64, 64), 64, 0, stream>>>(u1, VA_a, Vrs_a, nullptr, nullptr, Bc);
    s4_mid<<<512, 64, 0, stream>>>(s4a_ldt, Bc, Sini, nullptr, 64, 64);
    s4_gemm_c<64,6><<<dim3(16, 64), 256, 0, stream>>>(u1, Sini, TA_a, rs_a, nullptr, nullptr, ya);

    // conv block1: ya [64][16][8192] -> u2 [256][16][2048] bf16
    dim3 g1(32, 16, 1);
    conv_mfma<64, 1, false><<<g1, 256, 0, stream>>>(ya, wprep + 0,     b1b[0], u2, 8192, 2048, 0);
    conv_mfma<64, 2, true ><<<g1, 256, 0, stream>>>(ya, wprep + 12288, b1b[1], u2, 8192, 2048, 64);
    conv_mfma<64, 4, true ><<<g1, 256, 0, stream>>>(ya, wprep + 24576, b1b[2], u2, 8192, 2048, 128);
    conv_mfma<64, 8, true ><<<g1, 256, 0, stream>>>(ya, wprep + 36864, b1b[3], u2, 8192, 2048, 192);
    bn_stats<<<256, 256, 0, stream>>>(u2, bn1_g, bn1_b, sc1, sh1, 16*2048, 63);

    // s4b: H=256, NCH=16 (L=2048)
    s4_gemm_a<16,4><<<dim3(16, 256), 64, 0, stream>>>(u2, VA_b, Vrs_b, sc1, sh1, Bc);
    s4_mid<<<2048, 64, 0, stream>>>(s4b_ldt, Bc, Sini, nullptr, 256, 16);
    s4_gemm_c<16,4><<<dim3(4, 256), 256, 0, stream>>>(u2, Sini, TA_b, rs_b, sc1, sh1, yb);

    // conv block2: yb [256][16][2048] -> u3 [1024][16][512] bf16
    dim3 g2(8, 16, 4);
    conv_mfma<256, 1, false><<<g2, 256, 0, stream>>>(yb, wprep + 49152,  b2b[0], u3, 2048, 512, 0);
    conv_mfma<256, 2, true ><<<g2, 256, 0, stream>>>(yb, wprep + 245760, b2b[1], u3, 2048, 512, 256);
    conv_mfma<256, 4, true ><<<g2, 256, 0, stream>>>(yb, wprep + 442368, b2b[2], u3, 2048, 512, 512);
    conv_mfma<256, 8, true ><<<g2, 256, 0, stream>>>(yb, wprep + 638976, b2b[3], u3, 2048, 512, 768);
    bn_stats<<<1024, 256, 0, stream>>>(u3, bn2_g, bn2_b, sc2, sh2, 16*512, 255);

    // s4c: H=1024, NCH=4 (L=512); only final state needed.
    // yb is dead now -> reuse its 16.8 MB slot for VA_c (exact fit).
    prep_va<<<1024, 128, 0, stream>>>(s4c_ldt, VA_c, Vrs_c);
    s4_gemm_a<4,2><<<dim3(4, 1024), 64, 0, stream>>>(u3, VA_c, Vrs_c, sc2, sh2, Bc);
    s4_mid<<<8192, 64, 0, stream>>>(s4c_ldt, Bc, Sini, Sfin, 1024, 4);
    s4c_last<<<64, 256, 0, stream>>>(Sfin, u3, sc2, sh2, s4c_ldt, s4c_C, s4c_D, x3l);

    // decoder head
    dec_kernel<<<16, 256, 0, stream>>>(x3l, dec1_w, dec1_b, dec2_w, dec2_b, out);
}

// Round 5
// 419.639 us; speedup vs baseline: 2.9422x; 1.1616x over previous
//
#include <hip/hip_runtime.h>
#include <math.h>

#define PI_F 3.14159265358979323846f

typedef __attribute__((ext_vector_type(8))) short short8;
typedef __attribute__((ext_vector_type(4))) float f32x4;

__device__ __forceinline__ unsigned short f2bf(float f) {
    unsigned int u = __float_as_uint(f);
    unsigned int r = (u + 0x7fffu + ((u >> 16) & 1u)) >> 16;
    return (unsigned short)r;
}
__device__ __forceinline__ float bf2f(unsigned short v) {
    return __uint_as_float((unsigned int)v << 16);
}

// ---------------- encoder: x[16][8192][2] -> u1 bf16 [64][16][8192] ----------------
__global__ __launch_bounds__(256) void enc_kernel(
    const float* __restrict__ x, const float* __restrict__ ew,
    const float* __restrict__ eb, unsigned short* __restrict__ u1)
{
    int idx = blockIdx.x * 256 + threadIdx.x;   // 64*16*2048 threads, 4 t each
    int t4 = idx & 2047;
    int b  = (idx >> 11) & 15;
    int h  = idx >> 15;
    float w0 = ew[2*h], w1 = ew[2*h+1], bb = eb[h];
    const float* xp = x + ((size_t)b*8192 + (size_t)t4*4)*2;
    float4 a = *(const float4*)xp;
    float4 c = *(const float4*)(xp + 4);
    ushort4 o;
    o.x = f2bf(fmaf(w0, a.x, fmaf(w1, a.y, bb)));
    o.y = f2bf(fmaf(w0, a.z, fmaf(w1, a.w, bb)));
    o.z = f2bf(fmaf(w0, c.x, fmaf(w1, c.y, bb)));
    o.w = f2bf(fmaf(w0, c.z, fmaf(w1, c.w, bb)));
    *(ushort4*)(u1 + ((size_t)h*16 + b)*8192 + (size_t)t4*4) = o;
}

// ---------------- conv weight prep: fp32 [O][Cin][3] -> bf16 A-frag [kb][o][kk] ------
__global__ __launch_bounds__(256) void prep_w(
    const float* __restrict__ w0, const float* __restrict__ w1,
    const float* __restrict__ w2, const float* __restrict__ w3,
    const float* __restrict__ w4, const float* __restrict__ w5,
    const float* __restrict__ w6, const float* __restrict__ w7,
    unsigned short* __restrict__ wprep)
{
    int id = blockIdx.y;
    const float* src; int Cin; size_t doff;
    switch (id) {
        case 0: src = w0; Cin = 64;  doff = 0;      break;
        case 1: src = w1; Cin = 64;  doff = 12288;  break;
        case 2: src = w2; Cin = 64;  doff = 24576;  break;
        case 3: src = w3; Cin = 64;  doff = 36864;  break;
        case 4: src = w4; Cin = 256; doff = 49152;  break;
        case 5: src = w5; Cin = 256; doff = 245760; break;
        case 6: src = w6; Cin = 256; doff = 442368; break;
        default: src = w7; Cin = 256; doff = 638976; break;
    }
    int e = blockIdx.x * 256 + threadIdx.x;
    if (e >= Cin * Cin * 3) return;
    int kb  = e / (Cin * 32);
    int rem = e - kb * (Cin * 32);
    int o   = rem >> 5;
    int kk  = rem & 31;
    int cch = kb / 6, t6 = kb % 6, k = t6 >> 1, chalf = t6 & 1;
    int c = cch * 64 + chalf * 32 + kk;
    wprep[doff + e] = f2bf(src[((size_t)o * Cin + c) * 3 + k]);
}

// ---------------- S4 prep: build per-h MFMA A-matrices (coalesced writes) ----------
// TA[h][kb(6)][m(128)][kk(32)]: kb 0..3 Toeplitz K'[m-col], kb 4..5 W[m][j]
// VA[h][kb(4)][row(64)][kk(32)]: V[2n+ri][s] = w^(127-s) Re/Im
// rs[h][128]: prefix sums of K'; Vrs[h][64]: rowsum of V
__global__ __launch_bounds__(128) void prep_s4(
    const float* __restrict__ log_dt, const float* __restrict__ C2,
    const float* __restrict__ Dv,
    unsigned short* __restrict__ TA, unsigned short* __restrict__ VA,
    float* __restrict__ rs, float* __restrict__ Vrs)
{
    int h = blockIdx.x, t = threadIdx.x;
    __shared__ float cn[64];
    __shared__ float sK[128];
    __shared__ unsigned short s_w[128 * 66];   // W staged [m][j], pad 66
    float dt = expf(log_dt[h]);
    if (t < 32) {
        int n = t;
        float e = expf(-0.5f*dt);
        float s_, c_; sincosf(PI_F*dt*n, &s_, &c_);
        float wr = e*c_, wi = e*s_;
        float ar = -0.5f, ai = PI_F*n;
        float den = 1.f/(ar*ar + ai*ai);
        float tr = wr - 1.f, ti = wi;
        float qr = (tr*ar + ti*ai)*den;
        float qi = (ti*ar - tr*ai)*den;
        float c2r = C2[((size_t)h*32+n)*2], c2i = C2[((size_t)h*32+n)*2+1];
        cn[2*n]   = 2.f*(c2r*qr - c2i*qi);
        cn[2*n+1] = 2.f*(c2r*qi + c2i*qr);
        // Vrs = sum_{j=0}^{127} w^j = (1 - w^128)/(1 - w)
        float e128 = expf(-64.f*dt);
        float s2, c2v; sincosf(PI_F*dt*n*128.f, &s2, &c2v);
        float pr = 1.f - e128*c2v, pim = -e128*s2;
        float dr = 1.f - wr, di = -wi;
        float dd = 1.f/(dr*dr + di*di);
        Vrs[(size_t)h*64 + 2*n]   = (pr*dr + pim*di)*dd;
        Vrs[(size_t)h*64 + 2*n+1] = (pim*dr - pr*di)*dd;
    }
    __syncthreads();
    // phase 1: K[t] (each thread one tap)
    {
        float em = expf(-0.5f*dt*t);
        float Kt = 0.f;
        for (int n = 0; n < 32; n++) {
            float s_, c_; sincosf(PI_F*dt*(float)(n*t), &s_, &c_);
            Kt += cn[2*n]*em*c_ - cn[2*n+1]*em*s_;
        }
        sK[t] = Kt + (t == 0 ? Dv[h] : 0.f);
    }
    // phase 2: wave0 (t<64) builds W columns into LDS; wave1 builds V rows direct
    if (t < 64) {
        int n = t >> 1, ri = t & 1;
        float e = expf(-0.5f*dt);
        float s_, c_; sincosf(PI_F*dt*n, &s_, &c_);
        float wr = e*c_, wi = e*s_;
        float crn = cn[2*n], cin = cn[2*n+1];
        float pr = wr, pim = wi;                    // w^(m+1), m=0
        for (int m = 0; m < 128; m++) {
            float re = crn*pr - cin*pim;
            float im = crn*pim + cin*pr;
            s_w[m*66 + t] = f2bf(ri ? -im : re);
            float nr = pr*wr - pim*wi;
            float ni = pr*wi + pim*wr;
            pr = nr; pim = ni;
        }
    } else {
        int r = t - 64; int n = r >> 1, ri = r & 1;
        float e = expf(-0.5f*dt);
        float s_, c_; sincosf(PI_F*dt*n, &s_, &c_);
        float wr = e*c_, wi = e*s_;
        float cr2 = 1.f, ci2 = 0.f;                 // w^0
        for (int kb = 3; kb >= 0; kb--) {
            unsigned short buf[32];
            for (int kk = 31; kk >= 0; kk--) {
                buf[kk] = f2bf(ri ? ci2 : cr2);
                float nr = cr2*wr - ci2*wi;
                float ni = cr2*wi + ci2*wr;
                cr2 = nr; ci2 = ni;
            }
            uint4* dst = (uint4*)&VA[(((size_t)h*4 + kb)*64 + r)*32];
            uint4* src = (uint4*)buf;
            dst[0]=src[0]; dst[1]=src[1]; dst[2]=src[2]; dst[3]=src[3];
        }
    }
    __syncthreads();
    // prefix sum for BN shift
    {
        float acc = 0.f;
        for (int tau = 0; tau <= t; tau++) acc += sK[tau];
        rs[(size_t)h*128 + t] = acc;
    }
    // Toeplitz row t, buffered uint4 stores
    for (int kb = 0; kb < 4; kb++) {
        unsigned short tb[32];
#pragma unroll
        for (int kk = 0; kk < 32; kk++) {
            int col = kb*32 + kk;
            tb[kk] = f2bf((col <= t) ? sK[t - col] : 0.f);
        }
        uint4* dst = (uint4*)&TA[(((size_t)h*6 + kb)*128 + t)*32];
        uint4* src = (uint4*)tb;
        dst[0]=src[0]; dst[1]=src[1]; dst[2]=src[2]; dst[3]=src[3];
    }
    // W copy-out, coalesced: 1024 uint4 over kb'(2) x m(128) x kkg(4)
    for (int i = t; i < 1024; i += 128) {
        int kb = i >> 9;             // 0..1
        int rem = i & 511;
        int m = rem >> 2, kkg = rem & 3;
        *(uint4*)&TA[(((size_t)h*6 + 4 + kb)*128 + m)*32 + kkg*8] =
            *(const uint4*)&s_w[m*66 + kb*32 + kkg*8];
    }
}

// ---------------- slim prep (s4c): V rows + rowsums, coalesced ----------------
__global__ __launch_bounds__(64) void prep_va(
    const float* __restrict__ log_dt,
    unsigned short* __restrict__ VA, float* __restrict__ Vrs)
{
    int h = blockIdx.x, t = threadIdx.x;     // t = row = 2n+ri
    int n = t >> 1, ri = t & 1;
    float dt = expf(log_dt[h]);
    float e = expf(-0.5f*dt);
    float s_, c_; sincosf(PI_F*dt*n, &s_, &c_);
    float wr = e*c_, wi = e*s_;
    float cr2 = 1.f, ci2 = 0.f;              // w^0 -> col 127
    for (int kb = 3; kb >= 0; kb--) {
        unsigned short buf[32];
        for (int kk = 31; kk >= 0; kk--) {
            buf[kk] = f2bf(ri ? ci2 : cr2);
            float nr = cr2*wr - ci2*wi;
            float ni = cr2*wi + ci2*wr;
            cr2 = nr; ci2 = ni;
        }
        uint4* dst = (uint4*)&VA[(((size_t)h*4 + kb)*64 + t)*32];
        uint4* src = (uint4*)buf;
        dst[0]=src[0]; dst[1]=src[1]; dst[2]=src[2]; dst[3]=src[3];
    }
    if (ri == 0) {
        float e128 = expf(-64.f*dt);
        float s2, c2v; sincosf(PI_F*dt*n*128.f, &s2, &c2v);
        float pr = 1.f - e128*c2v, pim = -e128*s2;
        float dr = 1.f - wr, di = -wi;
        float dd = 1.f/(dr*dr + di*di);
        Vrs[(size_t)h*64 + 2*n]   = (pr*dr + pim*di)*dd;
        Vrs[(size_t)h*64 + 2*n+1] = (pim*dr - pr*di)*dd;
    }
}

// ---------------- S4 pass A (GEMM): chunk end-states E = V @ u ----------------
template<int NCH, int LOGNCH>
__global__ __launch_bounds__(64) void s4_gemm_a(
    const unsigned short* __restrict__ u, const unsigned short* __restrict__ VA,
    const float* __restrict__ Vrs, const float* __restrict__ sc,
    const float* __restrict__ sh, float* __restrict__ Bc)
{
    const int L = NCH * 128;
    int h = blockIdx.y;
    int lane = threadIdx.x;
    int nl = lane & 15, g = lane >> 4;
    int col = blockIdx.x * 16 + nl;
    int b = col >> LOGNCH, c = col & (NCH - 1);
    const unsigned short* up = u + ((size_t)h*16 + b)*L + c*128;
    f32x4 acc[4];
#pragma unroll
    for (int mt = 0; mt < 4; mt++) acc[mt] = (f32x4){0.f,0.f,0.f,0.f};
#pragma unroll
    for (int kb = 0; kb < 4; kb++) {
        short8 bf = *(const short8*)(up + kb*32 + g*8);
#pragma unroll
        for (int mt = 0; mt < 4; mt++) {
            short8 af = *(const short8*)(VA + (((size_t)h*4 + kb)*64 + mt*16 + nl)*32 + g*8);
            acc[mt] = __builtin_amdgcn_mfma_f32_16x16x32_bf16(af, bf, acc[mt], 0, 0, 0);
        }
    }
    float scv = sc ? sc[h] : 1.f;
    float shv = sh ? sh[h] : 0.f;
    float* bp = Bc + (((size_t)h*16 + b)*NCH + c)*64;
#pragma unroll
    for (int mt = 0; mt < 4; mt++) {
        int j0 = mt*16 + g*4;
        float4 vr = *(const float4*)(Vrs + (size_t)h*64 + j0);
        float4 o;
        o.x = fmaf(scv, acc[mt][0], shv*vr.x);
        o.y = fmaf(scv, acc[mt][1], shv*vr.y);
        o.z = fmaf(scv, acc[mt][2], shv*vr.z);
        o.w = fmaf(scv, acc[mt][3], shv*vr.w);
        *(float4*)(bp + j0) = o;
    }
}

// ---------------- S4 mid: chunk-level scan (w^128 via 7 squarings) ----------------
__global__ __launch_bounds__(64) void s4_mid(
    const float* __restrict__ log_dt, const float* __restrict__ Bc,
    float* __restrict__ Sinit, float* __restrict__ Sfinal,
    int H, int NCH)
{
    int gid = blockIdx.x * 64 + threadIdx.x;   // H*16*32
    int n = gid & 31;
    int tmp = gid >> 5;
    int b = tmp & 15;
    int h = tmp >> 4;
    float dt = expf(log_dt[h]);
    float e = expf(-0.5f * dt);
    float s_, c_; sincosf(PI_F * dt * n, &s_, &c_);
    float wr = e * c_, wi = e * s_;
#pragma unroll
    for (int i = 0; i < 7; i++) { float r = wr*wr - wi*wi; float im = 2.f*wr*wi; wr = r; wi = im; }
    float Sr = 0.f, Si = 0.f;
    size_t base = (((size_t)h*16 + b)*NCH)*64 + 2*n;
    for (int c = 0; c < NCH; c++) {
        float2 v; v.x = Sr; v.y = Si;
        *(float2*)(Sinit + base + (size_t)c*64) = v;
        float2 bc = *(const float2*)(Bc + base + (size_t)c*64);
        float r  = fmaf(wr, Sr, fmaf(-wi, Si, bc.x));
        float im = fmaf(wi, Sr, fmaf( wr, Si, bc.y));
        Sr = r; Si = im;
    }
    if (Sfinal) {
        float2 v; v.x = Sr; v.y = Si;
        *(float2*)(Sfinal + ((size_t)h*16 + b)*64 + 2*n) = v;
    }
}

// ---------------- S4 pass C (GEMM): y = sc*(T'@u) + sh*rs + W@Sinit ----------------
template<int NCH, int LOGNCH>
__global__ __launch_bounds__(256) void s4_gemm_c(
    const unsigned short* __restrict__ u, const float* __restrict__ Sini,
    const unsigned short* __restrict__ TA, const float* __restrict__ rs,
    const float* __restrict__ sc, const float* __restrict__ sh,
    unsigned short* __restrict__ yout)
{
    const int L = NCH * 128;
    __shared__ unsigned short s_u[64*200];   // 25600 B
    __shared__ unsigned short s_s[64*72];    // 9216 B
    int h = blockIdx.y;
    int tid = threadIdx.x;
    int lane = tid & 63, wid = tid >> 6;
    int nl = lane & 15, g = lane >> 4;
    int col0 = blockIdx.x * 64;
    for (int i = tid; i < 1024; i += 256) {
        int cl = i >> 4, o = i & 15;
        int col = col0 + cl; int b = col >> LOGNCH, c = col & (NCH - 1);
        *(uint4*)&s_u[cl*200 + o*8] =
            *(const uint4*)&u[((size_t)h*16 + b)*L + c*128 + o*8];
    }
    for (int i = tid; i < 1024; i += 256) {
        int cl = i >> 4, o = i & 15;
        int col = col0 + cl; int b = col >> LOGNCH, c = col & (NCH - 1);
        float4 v = *(const float4*)&Sini[(((size_t)h*16 + b)*NCH + c)*64 + o*4];
        ushort4 q; q.x = f2bf(v.x); q.y = f2bf(v.y); q.z = f2bf(v.z); q.w = f2bf(v.w);
        *(ushort4*)&s_s[cl*72 + o*4] = q;
    }
    __syncthreads();
    f32x4 accT[2][4], accW[2][4];
#pragma unroll
    for (int a = 0; a < 2; a++)
#pragma unroll
        for (int j = 0; j < 4; j++) { accT[a][j] = (f32x4){0,0,0,0}; accW[a][j] = (f32x4){0,0,0,0}; }
#pragma unroll
    for (int kb = 0; kb < 4; kb++) {
        short8 bfr[4];
#pragma unroll
        for (int j = 0; j < 4; j++)
            bfr[j] = *(const short8*)&s_u[(j*16 + nl)*200 + kb*32 + g*8];
#pragma unroll
        for (int mt2 = 0; mt2 < 2; mt2++) {
            int mtile = wid*2 + mt2;
            short8 af = *(const short8*)&TA[(((size_t)h*6 + kb)*128 + mtile*16 + nl)*32 + g*8];
#pragma unroll
            for (int j = 0; j < 4; j++)
                accT[mt2][j] = __builtin_amdgcn_mfma_f32_16x16x32_bf16(af, bfr[j], accT[mt2][j], 0, 0, 0);
        }
    }
#pragma unroll
    for (int kw = 0; kw < 2; kw++) {
        short8 bfr[4];
#pragma unroll
        for (int j = 0; j < 4; j++)
            bfr[j] = *(const short8*)&s_s[(j*16 + nl)*72 + kw*32 + g*8];
#pragma unroll
        for (int mt2 = 0; mt2 < 2; mt2++) {
            int mtile = wid*2 + mt2;
            short8 af = *(const short8*)&TA[(((size_t)h*6 + 4 + kw)*128 + mtile*16 + nl)*32 + g*8];
#pragma unroll
            for (int j = 0; j < 4; j++)
                accW[mt2][j] = __builtin_amdgcn_mfma_f32_16x16x32_bf16(af, bfr[j], accW[mt2][j], 0, 0, 0);
        }
    }
    float scv = sc ? sc[h] : 1.f;
    float shv = sh ? sh[h] : 0.f;
#pragma unroll
    for (int mt2 = 0; mt2 < 2; mt2++) {
        int m0 = (wid*2 + mt2)*16 + g*4;
        float4 rsv = *(const float4*)&rs[(size_t)h*128 + m0];
#pragma unroll
        for (int j = 0; j < 4; j++) {
            int col = col0 + j*16 + nl; int b = col >> LOGNCH, c = col & (NCH - 1);
            ushort4 q;
            q.x = f2bf(fmaf(scv, accT[mt2][j][0], shv*rsv.x) + accW[mt2][j][0]);
            q.y = f2bf(fmaf(scv, accT[mt2][j][1], shv*rsv.y) + accW[mt2][j][1]);
            q.z = f2bf(fmaf(scv, accT[mt2][j][2], shv*rsv.z) + accW[mt2][j][2]);
            q.w = f2bf(fmaf(scv, accT[mt2][j][3], shv*rsv.w) + accW[mt2][j][3]);
            *(ushort4*)&yout[((size_t)h*16 + b)*L + c*128 + m0] = q;
        }
    }
}

// ---------------- fused 4-dilation conv block via MFMA ----------------
// computes all 4 dilated convs (dil = 1,2,4,8) from one LDS staging.
// u [CIN][16][Lin] bf16 -> out [4*CIN][16][Lout] bf16 (out ch = d*CIN + og + local)
template<int CIN>
__global__ __launch_bounds__(256) void conv_mfma4(
    const unsigned short* __restrict__ u, const unsigned short* __restrict__ wp,
    const float* __restrict__ bs0, const float* __restrict__ bs1,
    const float* __restrict__ bs2, const float* __restrict__ bs3,
    unsigned short* __restrict__ out, int Lin, int Lout)
{
    __shared__ unsigned short s_in[4*68*72];   // residue-planed [r][q][ch], 39168 B
    int tid = threadIdx.x;
    int lane = tid & 63, wid = tid >> 6;
    int nl = lane & 15, g = lane >> 4;
    int t0 = blockIdx.x * 64;
    int b  = blockIdx.y;
    int og = blockIdx.z * 64;
    const int P0 = t0 * 4 - 8;

    f32x4 acc[4][4];
#pragma unroll
    for (int d = 0; d < 4; d++)
#pragma unroll
        for (int f = 0; f < 4; f++) acc[d][f] = (f32x4){0.f,0.f,0.f,0.f};

    for (int cc0 = 0; cc0 < CIN; cc0 += 64) {
        if (cc0) __syncthreads();
        for (int i = tid; i < 2176; i += 256) {
            int ch = i & 63, po = i >> 6;          // po in [0,34)
            int p = P0 + po*8;
            const unsigned short* gp = u + ((size_t)(cc0+ch)*16 + b)*Lin;
            unsigned short tmp[8];
            if (p >= 0 && p + 8 <= Lin) {
                *(uint4*)tmp = *(const uint4*)(gp + p);
            } else {
#pragma unroll
                for (int j = 0; j < 8; j++) {
                    int pj = p + j;
                    tmp[j] = ((unsigned)pj < (unsigned)Lin) ? gp[pj] : (unsigned short)0;
                }
            }
#pragma unroll
            for (int j = 0; j < 8; j++) {
                int pl = po*8 + j;                 // 0..271
                s_in[((pl & 3)*68 + (pl >> 2))*72 + ch] = tmp[j];
            }
        }
        __syncthreads();
#pragma unroll
        for (int k = 0; k < 3; ++k) {
#pragma unroll
            for (int chalf = 0; chalf < 2; ++chalf) {
                int kb = (cc0/64)*6 + k*2 + chalf;
#pragma unroll
                for (int d = 0; d < 4; ++d) {
                    const int DIL = 1 << d;
                    const int off = (k - 1) * DIL + 8;     // 0..16
                    const int r = off & 3, s = off >> 2;
                    short8 afrag = *(const short8*)&wp[(size_t)d*(3*CIN*CIN) +
                        ((size_t)kb*CIN + og + wid*16 + nl)*32 + g*8];
#pragma unroll
                    for (int f = 0; f < 4; ++f) {
                        int q = f*16 + nl + s;
                        short8 bfrag = *(const short8*)&s_in[(r*68 + q)*72 + chalf*32 + g*8];
                        acc[d][f] = __builtin_amdgcn_mfma_f32_16x16x32_bf16(afrag, bfrag, acc[d][f], 0, 0, 0);
                    }
                }
            }
        }
    }
    const float* bptr[4] = {bs0, bs1, bs2, bs3};
#pragma unroll
    for (int d = 0; d < 4; ++d) {
#pragma unroll
        for (int f = 0; f < 4; ++f) {
            int t = t0 + f*16 + nl;
#pragma unroll
            for (int r2 = 0; r2 < 4; ++r2) {
                int o = og + wid*16 + g*4 + r2;
                float v = acc[d][f][r2] + bptr[d][o];
                if (d) v = v >= 0.f ? v : 0.3f*v;
                out[((size_t)(d*CIN + o)*16 + b)*Lout + t] = f2bf(v);
            }
        }
    }
}

// ---------------- BN stats from bf16 [ch][b][t] ----------------
__global__ __launch_bounds__(256) void bn_stats(
    const unsigned short* __restrict__ x, const float* __restrict__ g,
    const float* __restrict__ bb, float* __restrict__ sc, float* __restrict__ sh,
    int n, int gmask)
{
    int ch = blockIdx.x;
    const unsigned short* xp = x + (size_t)ch * n;
    float s1 = 0.f, s2 = 0.f;
    for (int i = threadIdx.x*8; i < n; i += 2048) {
        uint4 raw = *(const uint4*)(xp + i);
        unsigned short us[8]; *(uint4*)us = raw;
#pragma unroll
        for (int j = 0; j < 8; j++) {
            float v = bf2f(us[j]);
            s1 += v; s2 += v*v;
        }
    }
    for (int o = 32; o > 0; o >>= 1) { s1 += __shfl_down(s1, o); s2 += __shfl_down(s2, o); }
    __shared__ float p1[4], p2[4];
    int wid = threadIdx.x >> 6;
    if ((threadIdx.x & 63) == 0) { p1[wid] = s1; p2[wid] = s2; }
    __syncthreads();
    if (threadIdx.x == 0) {
        s1 = p1[0] + p1[1] + p1[2] + p1[3];
        s2 = p2[0] + p2[1] + p2[2] + p2[3];
        float m = s1 / n;
        float var = s2 / n - m*m;
        float rstd = rsqrtf(var + 1e-5f);
        float scale = g[ch & gmask] * rstd;
        sc[ch] = scale;
        sh[ch] = fmaf(-m, scale, bb[ch & gmask]);
    }
}

// ---------------- s4c final-state -> x3[:, :, 511] ----------------
__global__ __launch_bounds__(256) void s4c_last(
    const float* __restrict__ Sfinal, const unsigned short* __restrict__ u3,
    const float* __restrict__ sc, const float* __restrict__ sh,
    const float* __restrict__ log_dt, const float* __restrict__ C2,
    const float* __restrict__ Dv, float* __restrict__ x3last)
{
    int gid = blockIdx.x*256 + threadIdx.x;  // 16*1024
    int h = gid & 1023;
    int b = gid >> 10;
    float dt = expf(log_dt[h]);
    float e = expf(-0.5f * dt);
    const float* sp = Sfinal + ((size_t)h*16 + b)*64;
    float aR = 0.f, aI = 0.f;
#pragma unroll
    for (int n = 0; n < 32; n++) {
        float s_, c_; sincosf(PI_F * dt * n, &s_, &c_);
        float wr = e*c_, wi = e*s_;
        float ar = -0.5f, ai = PI_F * n;
        float den = 1.f / (ar*ar + ai*ai);
        float tr = wr - 1.f, ti = wi;
        float qr = (tr*ar + ti*ai) * den;
        float qi = (ti*ar - tr*ai) * den;
        float c2r = C2[((size_t)h*32 + n)*2], c2i = C2[((size_t)h*32 + n)*2 + 1];
        float crv = c2r*qr - c2i*qi, civ = c2r*qi + c2i*qr;
        aR = fmaf(crv, sp[2*n],   aR);
        aI = fmaf(civ, sp[2*n+1], aI);
    }
    float uv = fmaf(sc[h], bf2f(u3[((size_t)h*16 + b)*512 + 511]), sh[h]);
    x3last[b*1024 + h] = 2.f*(aR - aI) + Dv[h]*uv;
}

// ---------------- decoder head ----------------
__global__ __launch_bounds__(256) void dec_kernel(
    const float* __restrict__ x3last, const float* __restrict__ w1, const float* __restrict__ b1,
    const float* __restrict__ w2, const float* __restrict__ b2, float* __restrict__ out)
{
    __shared__ float xs[1024];
    int b = blockIdx.x, tid = threadIdx.x;
    for (int i = tid; i < 1024; i += 256) xs[i] = x3last[b*1024 + i];
    __syncthreads();
    float z = b1[tid];
    const float* wpt = w1 + (size_t)tid*1024;
    for (int i = 0; i < 1024; i += 4) {
        float4 wv = *(const float4*)(wpt + i);
        z = fmaf(wv.x, xs[i],   z);
        z = fmaf(wv.y, xs[i+1], z);
        z = fmaf(wv.z, xs[i+2], z);
        z = fmaf(wv.w, xs[i+3], z);
    }
    float v = w2[tid] * z;
    for (int o = 32; o > 0; o >>= 1) v += __shfl_down(v, o);
    __shared__ float ps[4];
    if ((tid & 63) == 0) ps[tid >> 6] = v;
    __syncthreads();
    if (tid == 0) out[b] = ps[0] + ps[1] + ps[2] + ps[3] + b2[0];
}

extern "C" void kernel_launch(void* const* d_in, const int* in_sizes, int n_in,
                              void* d_out, int out_size, void* d_ws, size_t ws_size,
                              hipStream_t stream)
{
    const float* x       = (const float*)d_in[0];
    const float* enc_w   = (const float*)d_in[1];
    const float* enc_b   = (const float*)d_in[2];
    const float* s4a_ldt = (const float*)d_in[3];
    const float* s4a_C   = (const float*)d_in[4];
    const float* s4a_D   = (const float*)d_in[5];
    const float* s4b_ldt = (const float*)d_in[6];
    const float* s4b_C   = (const float*)d_in[7];
    const float* s4b_D   = (const float*)d_in[8];
    const float* s4c_ldt = (const float*)d_in[9];
    const float* s4c_C   = (const float*)d_in[10];
    const float* s4c_D   = (const float*)d_in[11];
    const float* b1w[4] = {(const float*)d_in[12], (const float*)d_in[14], (const float*)d_in[16], (const float*)d_in[18]};
    const float* b1b[4] = {(const float*)d_in[13], (const float*)d_in[15], (const float*)d_in[17], (const float*)d_in[19]};
    const float* b2w[4] = {(const float*)d_in[20], (const float*)d_in[22], (const float*)d_in[24], (const float*)d_in[26]};
    const float* b2b[4] = {(const float*)d_in[21], (const float*)d_in[23], (const float*)d_in[25], (const float*)d_in[27]};
    const float* bn1_g  = (const float*)d_in[28];
    const float* bn1_b  = (const float*)d_in[29];
    const float* bn2_g  = (const float*)d_in[30];
    const float* bn2_b  = (const float*)d_in[31];
    const float* dec1_w = (const float*)d_in[32];
    const float* dec1_b = (const float*)d_in[33];
    const float* dec2_w = (const float*)d_in[34];
    const float* dec2_b = (const float*)d_in[35];
    float* out = (float*)d_out;

    char* ws = (char*)d_ws;
    unsigned short* u1    = (unsigned short*)(ws);              // 16.8 MB (also u3)
    unsigned short* u3    = u1;
    unsigned short* ya    = (unsigned short*)(ws + 16777216);   // 16.8 MB (also yb, later VA_c)
    unsigned short* yb    = ya;
    unsigned short* VA_c  = ya;                                 // reuse after conv2
    unsigned short* u2    = (unsigned short*)(ws + 33554432);   // 16.8 MB
    float*          Bc    = (float*)(ws + 50331648);            // 16.8 MB
    float*          Sini  = (float*)(ws + 67108864);            // 16.8 MB
    float*          Sfin  = (float*)(ws + 83886080);            // 4.2 MB
    unsigned short* wprep = (unsigned short*)(ws + 88080384);   // 1.67 MB
    unsigned short* TA_a  = (unsigned short*)(ws + 89751552);   // 3.15 MB
    unsigned short* TA_b  = (unsigned short*)(ws + 92897280);   // 12.6 MB
    unsigned short* VA_a  = (unsigned short*)(ws + 105480192);  // 1.05 MB
    unsigned short* VA_b  = (unsigned short*)(ws + 106528768);  // 4.2 MB
    float*          rs_a  = (float*)(ws + 110723072);           // 32 KB
    float*          rs_b  = (float*)(ws + 110755840);           // 128 KB
    float*          Vrs_a = (float*)(ws + 110886912);           // 16 KB
    float*          Vrs_b = (float*)(ws + 110903296);           // 64 KB
    float*          smallp= (float*)(ws + 110968832);
    float* sc1 = smallp;         // 256
    float* sh1 = smallp + 256;   // 256
    float* sc2 = smallp + 512;   // 1024
    float* sh2 = smallp + 1536;  // 1024
    float* x3l = smallp + 2560;  // 16384
    float*          Vrs_c = (float*)(ws + 111280128);           // 256 KB

    // prep (independent of data path)
    prep_w<<<dim3(768, 8), 256, 0, stream>>>(b1w[0], b1w[1], b1w[2], b1w[3],
                                             b2w[0], b2w[1], b2w[2], b2w[3], wprep);
    prep_s4<<<64, 128, 0, stream>>>(s4a_ldt, s4a_C, s4a_D, TA_a, VA_a, rs_a, Vrs_a);
    prep_s4<<<256, 128, 0, stream>>>(s4b_ldt, s4b_C, s4b_D, TA_b, VA_b, rs_b, Vrs_b);

    // encoder -> u1 bf16
    enc_kernel<<<8192, 256, 0, stream>>>(x, enc_w, enc_b, u1);

    // s4a: H=64, NCH=64 (L=8192)
    s4_gemm_a<64,6><<<dim3(64, 64), 64, 0, stream>>>(u1, VA_a, Vrs_a, nullptr, nullptr, Bc);
    s4_mid<<<512, 64, 0, stream>>>(s4a_ldt, Bc, Sini, nullptr, 64, 64);
    s4_gemm_c<64,6><<<dim3(16, 64), 256, 0, stream>>>(u1, Sini, TA_a, rs_a, nullptr, nullptr, ya);

    // conv block1 (fused 4 dilations): ya [64][16][8192] -> u2 [256][16][2048]
    conv_mfma4<64><<<dim3(32, 16, 1), 256, 0, stream>>>(
        ya, wprep, b1b[0], b1b[1], b1b[2], b1b[3], u2, 8192, 2048);
    bn_stats<<<256, 256, 0, stream>>>(u2, bn1_g, bn1_b, sc1, sh1, 16*2048, 63);

    // s4b: H=256, NCH=16 (L=2048)
    s4_gemm_a<16,4><<<dim3(16, 256), 64, 0, stream>>>(u2, VA_b, Vrs_b, sc1, sh1, Bc);
    s4_mid<<<2048, 64, 0, stream>>>(s4b_ldt, Bc, Sini, nullptr, 256, 16);
    s4_gemm_c<16,4><<<dim3(4, 256), 256, 0, stream>>>(u2, Sini, TA_b, rs_b, sc1, sh1, yb);

    // conv block2 (fused 4 dilations): yb [256][16][2048] -> u3 [1024][16][512]
    conv_mfma4<256><<<dim3(8, 16, 4), 256, 0, stream>>>(
        yb, wprep + 49152, b2b[0], b2b[1], b2b[2], b2b[3], u3, 2048, 512);
    bn_stats<<<1024, 256, 0, stream>>>(u3, bn2_g, bn2_b, sc2, sh2, 16*512, 255);

    // s4c: H=1024, NCH=4 (L=512); only final state needed.
    // yb is dead now -> reuse its 16.8 MB slot for VA_c (exact fit).
    prep_va<<<1024, 64, 0, stream>>>(s4c_ldt, VA_c, Vrs_c);
    s4_gemm_a<4,2><<<dim3(4, 1024), 64, 0, stream>>>(u3, VA_c, Vrs_c, sc2, sh2, Bc);
    s4_mid<<<8192, 64, 0, stream>>>(s4c_ldt, Bc, Sini, Sfin, 1024, 4);
    s4c_last<<<64, 256, 0, stream>>>(Sfin, u3, sc2, sh2, s4c_ldt, s4c_C, s4c_D, x3l);

    // decoder head
    dec_kernel<<<16, 256, 0, stream>>>(x3l, dec1_w, dec1_b, dec2_w, dec2_b, out);
}